// Round 1
// baseline (768.312 us; speedup 1.0000x reference)
//
#include <hip/hip_runtime.h>

// ---------------- kernels ----------------

__global__ void k_deg_init(float* deg, int n) {
    int i = blockIdx.x * blockDim.x + threadIdx.x;
    if (i < n) deg[i] = 1.0f;  // self-loop
}

__global__ void k_deg_count(const int* __restrict__ dst, float* deg, int E) {
    int i = blockIdx.x * blockDim.x + threadIdx.x;
    int stride = gridDim.x * blockDim.x;
    for (; i < E; i += stride) {
        atomicAdd(&deg[dst[i]], 1.0f);
    }
}

__global__ void k_dinv(float* deg, int n) {
    int i = blockIdx.x * blockDim.x + threadIdx.x;
    if (i < n) deg[i] = rsqrtf(deg[i]);  // deg>0 always (self-loops)
}

// h1 = x @ W1   (x: n x 128, W1: 128 x 64)
__global__ __launch_bounds__(256) void k_gemm1(const float* __restrict__ x,
                                               const float* __restrict__ W,
                                               float* __restrict__ h, int n) {
    __shared__ float Wl[128 * 64];
    int tid = threadIdx.x;
    for (int i = tid; i < 128 * 64; i += 256) Wl[i] = W[i];
    __syncthreads();
    int col = tid & 63;
    int r   = tid >> 6;          // 0..3
    int row = blockIdx.x * 4 + r;
    if (row >= n) return;
    const float* xr = x + (size_t)row * 128;
    float acc = 0.0f;
#pragma unroll
    for (int k = 0; k < 128; k += 4) {
        float4 xv = *reinterpret_cast<const float4*>(xr + k);
        acc += xv.x * Wl[(k + 0) * 64 + col];
        acc += xv.y * Wl[(k + 1) * 64 + col];
        acc += xv.z * Wl[(k + 2) * 64 + col];
        acc += xv.w * Wl[(k + 3) * 64 + col];
    }
    h[(size_t)row * 64 + col] = acc;
}

// agg1[i][c] = h1[i][c] * dinv[i]^2   (self-loop message)
__global__ void k_selfloop1(const float* __restrict__ h, const float* __restrict__ dinv,
                            float* __restrict__ agg, int n) {
    size_t i = (size_t)blockIdx.x * blockDim.x + threadIdx.x;
    size_t total = (size_t)n * 64;
    if (i < total) {
        int row = (int)(i >> 6);
        float d = dinv[row];
        agg[i] = h[i] * d * d;
    }
}

// scatter layer 1: 64 channels, one wave per edge
__global__ void k_scatter1(const int* __restrict__ src, const int* __restrict__ dst,
                           const float* __restrict__ h, const float* __restrict__ dinv,
                           float* __restrict__ agg, int E) {
    long long gid = (long long)blockIdx.x * blockDim.x + threadIdx.x;
    long long total = (long long)E * 64;
    long long stride = (long long)gridDim.x * blockDim.x;
    for (; gid < total; gid += stride) {
        int e = (int)(gid >> 6);
        int c = (int)(gid & 63);
        int s = src[e];
        int d = dst[e];
        float norm = dinv[s] * dinv[d];
        atomicAdd(&agg[(size_t)d * 64 + c], h[(size_t)s * 64 + c] * norm);
    }
}

// h2 = relu(agg1 + b1) @ W2   (agg1: n x 64, W2: 64 x 32)
__global__ __launch_bounds__(256) void k_gemm2(const float* __restrict__ agg,
                                               const float* __restrict__ b1,
                                               const float* __restrict__ W2,
                                               float* __restrict__ h2, int n) {
    __shared__ float Wl[64 * 32];
    __shared__ float bl[64];
    int tid = threadIdx.x;
    for (int i = tid; i < 64 * 32; i += 256) Wl[i] = W2[i];
    if (tid < 64) bl[tid] = b1[tid];
    __syncthreads();
    int col = tid & 31;
    int r   = tid >> 5;          // 0..7
    int row = blockIdx.x * 8 + r;
    if (row >= n) return;
    const float* ar = agg + (size_t)row * 64;
    float acc = 0.0f;
#pragma unroll
    for (int k = 0; k < 64; k++) {
        float v = ar[k] + bl[k];
        v = v > 0.0f ? v : 0.0f;
        acc += v * Wl[k * 32 + col];
    }
    h2[(size_t)row * 32 + col] = acc;
}

// out[i][c] = h2[i][c]*dinv[i]^2 + b2[c]   (self-loop + bias, also inits d_out)
__global__ void k_selfloop2(const float* __restrict__ h2, const float* __restrict__ dinv,
                            const float* __restrict__ b2, float* __restrict__ out, int n) {
    size_t i = (size_t)blockIdx.x * blockDim.x + threadIdx.x;
    size_t total = (size_t)n * 32;
    if (i < total) {
        int row = (int)(i >> 5);
        int c = (int)(i & 31);
        float d = dinv[row];
        out[i] = h2[i] * d * d + b2[c];
    }
}

// scatter layer 2: 32 channels, 2 edges per wave
__global__ void k_scatter2(const int* __restrict__ src, const int* __restrict__ dst,
                           const float* __restrict__ h2, const float* __restrict__ dinv,
                           float* __restrict__ out, int E) {
    long long gid = (long long)blockIdx.x * blockDim.x + threadIdx.x;
    long long total = (long long)E * 32;
    long long stride = (long long)gridDim.x * blockDim.x;
    for (; gid < total; gid += stride) {
        int e = (int)(gid >> 5);
        int c = (int)(gid & 31);
        int s = src[e];
        int d = dst[e];
        float norm = dinv[s] * dinv[d];
        atomicAdd(&out[(size_t)d * 32 + c], h2[(size_t)s * 32 + c] * norm);
    }
}

// ---------------- launch ----------------

extern "C" void kernel_launch(void* const* d_in, const int* in_sizes, int n_in,
                              void* d_out, int out_size, void* d_ws, size_t ws_size,
                              hipStream_t stream) {
    const float* x  = (const float*)d_in[0];
    const int*   ei = (const int*)d_in[1];
    const float* W1 = (const float*)d_in[2];
    const float* b1 = (const float*)d_in[3];
    const float* W2 = (const float*)d_in[4];
    const float* b2 = (const float*)d_in[5];
    float* out = (float*)d_out;

    const int n = in_sizes[0] / 128;
    const int E = in_sizes[1] / 2;
    const int* src = ei;
    const int* dst = ei + E;

    // workspace carve-out
    char* ws = (char*)d_ws;
    size_t off = 0;
    auto carve = [&](size_t bytes) {
        void* p = ws + off;
        off += (bytes + 255) & ~(size_t)255;
        return p;
    };
    float* dinv = (float*)carve((size_t)n * sizeof(float));        // deg -> dinv in place
    float* h1   = (float*)carve((size_t)n * 64 * sizeof(float));
    float* agg1 = (float*)carve((size_t)n * 64 * sizeof(float));
    float* h2   = (float*)carve((size_t)n * 32 * sizeof(float));

    const int B = 256;
    int gN   = (n + B - 1) / B;

    // 1. degree + dinv
    k_deg_init<<<gN, B, 0, stream>>>(dinv, n);
    k_deg_count<<<4096, B, 0, stream>>>(dst, dinv, E);
    k_dinv<<<gN, B, 0, stream>>>(dinv, n);

    // 2. h1 = x @ W1
    k_gemm1<<<(n + 3) / 4, B, 0, stream>>>(x, W1, h1, n);

    // 3. agg1 = selfloop + scatter
    {
        size_t total = (size_t)n * 64;
        k_selfloop1<<<(int)((total + B - 1) / B), B, 0, stream>>>(h1, dinv, agg1, n);
        k_scatter1<<<8192, B, 0, stream>>>(src, dst, h1, dinv, agg1, E);
    }

    // 4. h2 = relu(agg1 + b1) @ W2
    k_gemm2<<<(n + 7) / 8, B, 0, stream>>>(agg1, b1, W2, h2, n);

    // 5. out = selfloop2 + bias, then scatter
    {
        size_t total = (size_t)n * 32;
        k_selfloop2<<<(int)((total + B - 1) / B), B, 0, stream>>>(h2, dinv, b2, out, n);
        k_scatter2<<<8192, B, 0, stream>>>(src, dst, h2, dinv, out, E);
    }
}

// Round 2
// 536.780 us; speedup vs baseline: 1.4313x; 1.4313x over previous
//
#include <hip/hip_runtime.h>

// ---------------- CSR build ----------------

__global__ void k_zero_i(int* p, int n) {
    int i = blockIdx.x * blockDim.x + threadIdx.x;
    if (i < n) p[i] = 0;
}

__global__ void k_hist(const int* __restrict__ dst, int* __restrict__ cnt, int E) {
    int i = blockIdx.x * blockDim.x + threadIdx.x;
    if (i < E) atomicAdd(&cnt[dst[i]], 1);
}

__global__ void k_dinv(const int* __restrict__ cnt, float* __restrict__ dinv, int n) {
    int i = blockIdx.x * blockDim.x + threadIdx.x;
    if (i < n) dinv[i] = rsqrtf((float)(cnt[i] + 1));  // +1 self-loop
}

// block scans 1024 elements (256 thr x 4); writes exclusive scan + block sum
__global__ __launch_bounds__(256) void k_scan1(const int* __restrict__ cnt,
                                               int* __restrict__ out,
                                               int* __restrict__ bsum, int n) {
    __shared__ int sh[256];
    int t = threadIdx.x;
    int base = blockIdx.x * 1024 + t * 4;
    int v0 = base + 0 < n ? cnt[base + 0] : 0;
    int v1 = base + 1 < n ? cnt[base + 1] : 0;
    int v2 = base + 2 < n ? cnt[base + 2] : 0;
    int v3 = base + 3 < n ? cnt[base + 3] : 0;
    int s = v0 + v1 + v2 + v3;
    sh[t] = s;
    __syncthreads();
    for (int d = 1; d < 256; d <<= 1) {
        int x = (t >= d) ? sh[t - d] : 0;
        __syncthreads();
        sh[t] += x;
        __syncthreads();
    }
    int excl = sh[t] - s;
    if (base + 0 < n) out[base + 0] = excl;
    if (base + 1 < n) out[base + 1] = excl + v0;
    if (base + 2 < n) out[base + 2] = excl + v0 + v1;
    if (base + 3 < n) out[base + 3] = excl + v0 + v1 + v2;
    if (t == 255) bsum[blockIdx.x] = sh[255];
}

__global__ __launch_bounds__(256) void k_scan2(int* bsum, int nb) {
    __shared__ int sh[256];
    int t = threadIdx.x;
    int v = t < nb ? bsum[t] : 0;
    sh[t] = v;
    __syncthreads();
    for (int d = 1; d < 256; d <<= 1) {
        int x = (t >= d) ? sh[t - d] : 0;
        __syncthreads();
        sh[t] += x;
        __syncthreads();
    }
    if (t < nb) bsum[t] = sh[t] - v;  // exclusive
}

// finalize offsets (+block base), copy to cursor, set off[n]=E
__global__ void k_scan3(int* __restrict__ off, int* __restrict__ cur,
                        const int* __restrict__ bsum, int n, int E) {
    int i = blockIdx.x * blockDim.x + threadIdx.x;
    if (i < n) {
        int v = off[i] + bsum[i >> 10];
        off[i] = v;
        cur[i] = v;
    }
    if (i == 0) off[n] = E;
}

__global__ void k_fill(const int* __restrict__ src, const int* __restrict__ dst,
                       int* __restrict__ cur, int* __restrict__ esrc, int E) {
    int i = blockIdx.x * blockDim.x + threadIdx.x;
    if (i < E) {
        int pos = atomicAdd(&cur[dst[i]], 1);
        esrc[pos] = src[i];
    }
}

// ---------------- dense transforms ----------------

// h1p = (x @ W1) * dinv[row]   (x: n x 128, W1: 128 x 64)
__global__ __launch_bounds__(256) void k_gemm1(const float* __restrict__ x,
                                               const float* __restrict__ W,
                                               const float* __restrict__ dinv,
                                               float* __restrict__ h, int n) {
    __shared__ float Wl[128 * 64];
    int tid = threadIdx.x;
    for (int i = tid; i < 128 * 64; i += 256) Wl[i] = W[i];
    __syncthreads();
    int col = tid & 63;
    int r   = tid >> 6;
    int row = blockIdx.x * 4 + r;
    if (row >= n) return;
    const float* xr = x + (size_t)row * 128;
    float acc = 0.0f;
#pragma unroll
    for (int k = 0; k < 128; k += 4) {
        float4 xv = *reinterpret_cast<const float4*>(xr + k);
        acc += xv.x * Wl[(k + 0) * 64 + col];
        acc += xv.y * Wl[(k + 1) * 64 + col];
        acc += xv.z * Wl[(k + 2) * 64 + col];
        acc += xv.w * Wl[(k + 3) * 64 + col];
    }
    h[(size_t)row * 64 + col] = acc * dinv[row];
}

// h2p = (relu(agg1 + b1) @ W2) * dinv[row]   (agg1: n x 64, W2: 64 x 32)
__global__ __launch_bounds__(256) void k_gemm2(const float* __restrict__ agg,
                                               const float* __restrict__ b1,
                                               const float* __restrict__ W2,
                                               const float* __restrict__ dinv,
                                               float* __restrict__ h2, int n) {
    __shared__ float Wl[64 * 32];
    __shared__ float bl[64];
    int tid = threadIdx.x;
    for (int i = tid; i < 64 * 32; i += 256) Wl[i] = W2[i];
    if (tid < 64) bl[tid] = b1[tid];
    __syncthreads();
    int col = tid & 31;
    int r   = tid >> 5;
    int row = blockIdx.x * 8 + r;
    if (row >= n) return;
    const float* ar = agg + (size_t)row * 64;
    float acc = 0.0f;
#pragma unroll
    for (int k = 0; k < 64; k++) {
        float v = ar[k] + bl[k];
        v = v > 0.0f ? v : 0.0f;
        acc += v * Wl[k * 32 + col];
    }
    h2[(size_t)row * 32 + col] = acc * dinv[row];
}

// ---------------- pull aggregation ----------------

// one wave per node, 64 channels; agg[i] = (h1p[i] + sum_e h1p[src_e]) * dinv[i]
__global__ __launch_bounds__(256) void k_agg1(const float* __restrict__ h1p,
                                              const int* __restrict__ off,
                                              const int* __restrict__ esrc,
                                              const float* __restrict__ dinv,
                                              float* __restrict__ agg, int n) {
    int wid = (int)((blockIdx.x * blockDim.x + threadIdx.x) >> 6);
    int c = threadIdx.x & 63;
    if (wid >= n) return;
    int e0 = off[wid], e1 = off[wid + 1];
    float acc0 = h1p[(size_t)wid * 64 + c];  // self-loop (already * dinv[i])
    float acc1 = 0.0f;
    int e = e0;
    for (; e + 1 < e1; e += 2) {
        int s0 = esrc[e];
        int s1 = esrc[e + 1];
        acc0 += h1p[(size_t)s0 * 64 + c];
        acc1 += h1p[(size_t)s1 * 64 + c];
    }
    if (e < e1) acc1 += h1p[(size_t)esrc[e] * 64 + c];
    agg[(size_t)wid * 64 + c] = (acc0 + acc1) * dinv[wid];
}

// one wave per node, 32 channels, 2 edges/iter; writes final output with bias
__global__ __launch_bounds__(256) void k_agg2(const float* __restrict__ h2p,
                                              const int* __restrict__ off,
                                              const int* __restrict__ esrc,
                                              const float* __restrict__ dinv,
                                              const float* __restrict__ b2,
                                              float* __restrict__ out, int n) {
    int wid = (int)((blockIdx.x * blockDim.x + threadIdx.x) >> 6);
    int lane = threadIdx.x & 63;
    int c = lane & 31;
    int hi = lane >> 5;
    if (wid >= n) return;
    int e0 = off[wid], e1 = off[wid + 1];
    float acc = 0.0f;
    for (int e = e0 + hi; e < e1; e += 2) {
        int s = esrc[e];
        acc += h2p[(size_t)s * 32 + c];
    }
    acc += __shfl_xor(acc, 32);
    if (hi == 0) {
        acc += h2p[(size_t)wid * 32 + c];  // self-loop
        out[(size_t)wid * 32 + c] = acc * dinv[wid] + b2[c];
    }
}

// ---------------- launch ----------------

extern "C" void kernel_launch(void* const* d_in, const int* in_sizes, int n_in,
                              void* d_out, int out_size, void* d_ws, size_t ws_size,
                              hipStream_t stream) {
    const float* x  = (const float*)d_in[0];
    const int*   ei = (const int*)d_in[1];
    const float* W1 = (const float*)d_in[2];
    const float* b1 = (const float*)d_in[3];
    const float* W2 = (const float*)d_in[4];
    const float* b2 = (const float*)d_in[5];
    float* out = (float*)d_out;

    const int n = in_sizes[0] / 128;
    const int E = in_sizes[1] / 2;
    const int* src = ei;
    const int* dst = ei + E;

    char* ws = (char*)d_ws;
    size_t woff = 0;
    auto carve = [&](size_t bytes) {
        void* p = ws + woff;
        woff += (bytes + 255) & ~(size_t)255;
        return p;
    };
    int*   cnt  = (int*)carve((size_t)n * sizeof(int));          // reused as cursor
    int*   off  = (int*)carve((size_t)(n + 1) * sizeof(int));
    int*   bsum = (int*)carve(256 * sizeof(int));
    float* dinv = (float*)carve((size_t)n * sizeof(float));
    int*   esrc = (int*)carve((size_t)E * sizeof(int));
    float* h1p  = (float*)carve((size_t)n * 64 * sizeof(float)); // reused as h2p
    float* agg1 = (float*)carve((size_t)n * 64 * sizeof(float));
    float* h2p  = h1p;  // alias: h1p dead after k_agg1, h2p written by k_gemm2

    const int B = 256;
    const int gN = (n + B - 1) / B;
    const int gE = (E + B - 1) / B;
    const int nb = (n + 1023) / 1024;

    // CSR build + dinv
    k_zero_i<<<gN, B, 0, stream>>>(cnt, n);
    k_hist<<<gE, B, 0, stream>>>(dst, cnt, E);
    k_dinv<<<gN, B, 0, stream>>>(cnt, dinv, n);
    k_scan1<<<nb, B, 0, stream>>>(cnt, off, bsum, n);
    k_scan2<<<1, B, 0, stream>>>(bsum, nb);
    k_scan3<<<gN, B, 0, stream>>>(off, cnt, bsum, n, E);  // cnt becomes cursor
    k_fill<<<gE, B, 0, stream>>>(src, dst, cnt, esrc, E);

    // layer 1
    k_gemm1<<<(n + 3) / 4, B, 0, stream>>>(x, W1, dinv, h1p, n);
    k_agg1<<<(n + 3) / 4, B, 0, stream>>>(h1p, off, esrc, dinv, agg1, n);

    // layer 2
    k_gemm2<<<(n + 7) / 8, B, 0, stream>>>(agg1, b1, W2, dinv, h2p, n);
    k_agg2<<<(n + 3) / 4, B, 0, stream>>>(h2p, off, esrc, dinv, b2, out, n);
}

// Round 3
// 488.017 us; speedup vs baseline: 1.5744x; 1.0999x over previous
//
#include <hip/hip_runtime.h>

// ---------------- CSR build ----------------

__global__ void k_zero_i(int* p, int n) {
    int i = blockIdx.x * blockDim.x + threadIdx.x;
    if (i < n) p[i] = 0;
}

__global__ void k_hist(const int* __restrict__ dst, int* __restrict__ cnt, int E) {
    int i = blockIdx.x * blockDim.x + threadIdx.x;
    if (i < E) atomicAdd(&cnt[dst[i]], 1);
}

// block scans 1024 elements (256 thr x 4); writes exclusive scan + block sum + dinv
__global__ __launch_bounds__(256) void k_scan1(const int* __restrict__ cnt,
                                               int* __restrict__ out,
                                               int* __restrict__ bsum,
                                               float* __restrict__ dinv, int n) {
    __shared__ int sh[256];
    int t = threadIdx.x;
    int base = blockIdx.x * 1024 + t * 4;
    int v0 = base + 0 < n ? cnt[base + 0] : 0;
    int v1 = base + 1 < n ? cnt[base + 1] : 0;
    int v2 = base + 2 < n ? cnt[base + 2] : 0;
    int v3 = base + 3 < n ? cnt[base + 3] : 0;
    if (base + 0 < n) dinv[base + 0] = rsqrtf((float)(v0 + 1));
    if (base + 1 < n) dinv[base + 1] = rsqrtf((float)(v1 + 1));
    if (base + 2 < n) dinv[base + 2] = rsqrtf((float)(v2 + 1));
    if (base + 3 < n) dinv[base + 3] = rsqrtf((float)(v3 + 1));
    int s = v0 + v1 + v2 + v3;
    sh[t] = s;
    __syncthreads();
    for (int d = 1; d < 256; d <<= 1) {
        int x = (t >= d) ? sh[t - d] : 0;
        __syncthreads();
        sh[t] += x;
        __syncthreads();
    }
    int excl = sh[t] - s;
    if (base + 0 < n) out[base + 0] = excl;
    if (base + 1 < n) out[base + 1] = excl + v0;
    if (base + 2 < n) out[base + 2] = excl + v0 + v1;
    if (base + 3 < n) out[base + 3] = excl + v0 + v1 + v2;
    if (t == 255) bsum[blockIdx.x] = sh[255];
}

__global__ __launch_bounds__(256) void k_scan2(int* bsum, int nb) {
    __shared__ int sh[256];
    int t = threadIdx.x;
    int v = t < nb ? bsum[t] : 0;
    sh[t] = v;
    __syncthreads();
    for (int d = 1; d < 256; d <<= 1) {
        int x = (t >= d) ? sh[t - d] : 0;
        __syncthreads();
        sh[t] += x;
        __syncthreads();
    }
    if (t < nb) bsum[t] = sh[t] - v;  // exclusive
}

__global__ void k_scan3(int* __restrict__ off, int* __restrict__ cur,
                        const int* __restrict__ bsum, int n, int E) {
    int i = blockIdx.x * blockDim.x + threadIdx.x;
    if (i < n) {
        int v = off[i] + bsum[i >> 10];
        off[i] = v;
        cur[i] = v;
    }
    if (i == 0) off[n] = E;
}

__global__ void k_fill(const int* __restrict__ src, const int* __restrict__ dst,
                       int* __restrict__ cur, int* __restrict__ esrc, int E) {
    int i = blockIdx.x * blockDim.x + threadIdx.x;
    if (i < E) {
        int pos = atomicAdd(&cur[dst[i]], 1);
        esrc[pos] = src[i];
    }
}

// ---------------- gemm1: h1p = (x @ W1) * dinv[row] ----------------
// block: 32 rows x 64 cols, 128 threads, thread = 4x4 tile

__global__ __launch_bounds__(128) void k_gemm1(const float* __restrict__ x,
                                               const float* __restrict__ W,
                                               const float* __restrict__ dinv,
                                               float* __restrict__ h, int n) {
    __shared__ float Wl[128 * 64];
    __shared__ float xl[32 * 132];   // pad 132: bank = (4r+k)%32 -> 2-way only
    int tid = threadIdx.x;
    int rowBase = blockIdx.x * 32;
    // stage W (row-major [k][col], straight copy)
    for (int f = tid * 4; f < 128 * 64; f += 128 * 4)
        *(float4*)&Wl[f] = *(const float4*)&W[f];
    // stage x tile
#pragma unroll
    for (int it = 0; it < 8; it++) {
        int idx = it * 128 + tid;          // float4 index 0..1023
        int r = idx >> 5;
        int k0 = (idx & 31) * 4;
        float4 v = make_float4(0.f, 0.f, 0.f, 0.f);
        if (rowBase + r < n) v = *(const float4*)&x[(size_t)(rowBase + r) * 128 + k0];
        *(float4*)&xl[r * 132 + k0] = v;
    }
    __syncthreads();
    int cg = tid & 15;                      // 16 col-groups x 4 cols
    int rg = tid >> 4;                      // 8 row-groups x 4 rows
    const float* xr0 = &xl[(rg * 4 + 0) * 132];
    const float* xr1 = &xl[(rg * 4 + 1) * 132];
    const float* xr2 = &xl[(rg * 4 + 2) * 132];
    const float* xr3 = &xl[(rg * 4 + 3) * 132];
    const float* wp = &Wl[cg * 4];
    float acc[4][4] = {};
#pragma unroll 4
    for (int k = 0; k < 128; k++) {
        float4 wv = *(const float4*)&wp[k * 64];
        float x0 = xr0[k], x1 = xr1[k], x2 = xr2[k], x3 = xr3[k];
        acc[0][0] += x0 * wv.x; acc[0][1] += x0 * wv.y; acc[0][2] += x0 * wv.z; acc[0][3] += x0 * wv.w;
        acc[1][0] += x1 * wv.x; acc[1][1] += x1 * wv.y; acc[1][2] += x1 * wv.z; acc[1][3] += x1 * wv.w;
        acc[2][0] += x2 * wv.x; acc[2][1] += x2 * wv.y; acc[2][2] += x2 * wv.z; acc[2][3] += x2 * wv.w;
        acc[3][0] += x3 * wv.x; acc[3][1] += x3 * wv.y; acc[3][2] += x3 * wv.z; acc[3][3] += x3 * wv.w;
    }
#pragma unroll
    for (int i = 0; i < 4; i++) {
        int row = rowBase + rg * 4 + i;
        if (row < n) {
            float dv = dinv[row];
            float4 o = make_float4(acc[i][0] * dv, acc[i][1] * dv,
                                   acc[i][2] * dv, acc[i][3] * dv);
            *(float4*)&h[(size_t)row * 64 + cg * 4] = o;
        }
    }
}

// ---------------- fused agg1 + relu + gemm2 ----------------
// one wave per node (grid-stride): gather h1p -> agg (reg, per-lane channel),
// relu(agg*dinv + b1) -> per-wave LDS row -> gemm with W2 in registers -> h2p

__global__ __launch_bounds__(256) void k_agg1gemm2(const float* __restrict__ h1p,
                                                   const int* __restrict__ off,
                                                   const int* __restrict__ esrc,
                                                   const float* __restrict__ dinv,
                                                   const float* __restrict__ b1,
                                                   const float* __restrict__ W2,
                                                   float* __restrict__ h2p, int n) {
    __shared__ float aggL[4][64];
    int warp = threadIdx.x >> 6;
    int lane = threadIdx.x & 63;
    int j = lane & 31, hi = lane >> 5;
    // W2 fragment in registers: w2r[kk] = W2[(hi*32+kk)][j]
    float w2r[32];
#pragma unroll
    for (int kk = 0; kk < 32; kk++) w2r[kk] = W2[(hi * 32 + kk) * 32 + j];
    float bb = b1[lane];
    int nwaves = (gridDim.x * blockDim.x) >> 6;
    int wid0 = (int)((blockIdx.x * blockDim.x + threadIdx.x) >> 6);
    for (int wid = wid0; wid < n; wid += nwaves) {
        int e0 = off[wid], e1 = off[wid + 1];
        float acc0 = h1p[(size_t)wid * 64 + lane];  // self-loop (already * dinv)
        float acc1 = 0.0f;
        int e = e0;
        for (; e + 1 < e1; e += 2) {
            int s0 = esrc[e];
            int s1 = esrc[e + 1];
            acc0 += h1p[(size_t)s0 * 64 + lane];
            acc1 += h1p[(size_t)s1 * 64 + lane];
        }
        if (e < e1) acc1 += h1p[(size_t)esrc[e] * 64 + lane];
        float dv = dinv[wid];
        float a = (acc0 + acc1) * dv + bb;
        a = a > 0.0f ? a : 0.0f;
        aggL[warp][lane] = a;
        asm volatile("s_waitcnt lgkmcnt(0)" ::: "memory");  // wave-internal LDS sync
        float acc2 = 0.0f;
#pragma unroll
        for (int kk = 0; kk < 32; kk += 4) {
            float4 av = *(const float4*)&aggL[warp][hi * 32 + kk];
            acc2 += av.x * w2r[kk] + av.y * w2r[kk + 1] + av.z * w2r[kk + 2] + av.w * w2r[kk + 3];
        }
        acc2 += __shfl_xor(acc2, 32);
        if (hi == 0) h2p[(size_t)wid * 32 + j] = acc2 * dv;
    }
}

// ---------------- final aggregation -> out ----------------

__global__ __launch_bounds__(256) void k_agg2(const float* __restrict__ h2p,
                                              const int* __restrict__ off,
                                              const int* __restrict__ esrc,
                                              const float* __restrict__ dinv,
                                              const float* __restrict__ b2,
                                              float* __restrict__ out, int n) {
    int wid = (int)((blockIdx.x * blockDim.x + threadIdx.x) >> 6);
    int lane = threadIdx.x & 63;
    int c = lane & 31;
    int hi = lane >> 5;
    if (wid >= n) return;
    int e0 = off[wid], e1 = off[wid + 1];
    float acc = 0.0f;
    for (int e = e0 + hi; e < e1; e += 2) {
        int s = esrc[e];
        acc += h2p[(size_t)s * 32 + c];
    }
    acc += __shfl_xor(acc, 32);
    if (hi == 0) {
        acc += h2p[(size_t)wid * 32 + c];  // self-loop
        out[(size_t)wid * 32 + c] = acc * dinv[wid] + b2[c];
    }
}

// ---------------- launch ----------------

extern "C" void kernel_launch(void* const* d_in, const int* in_sizes, int n_in,
                              void* d_out, int out_size, void* d_ws, size_t ws_size,
                              hipStream_t stream) {
    const float* x  = (const float*)d_in[0];
    const int*   ei = (const int*)d_in[1];
    const float* W1 = (const float*)d_in[2];
    const float* b1 = (const float*)d_in[3];
    const float* W2 = (const float*)d_in[4];
    const float* b2 = (const float*)d_in[5];
    float* out = (float*)d_out;

    const int n = in_sizes[0] / 128;
    const int E = in_sizes[1] / 2;
    const int* src = ei;
    const int* dst = ei + E;

    char* ws = (char*)d_ws;
    size_t woff = 0;
    auto carve = [&](size_t bytes) {
        void* p = ws + woff;
        woff += (bytes + 255) & ~(size_t)255;
        return p;
    };
    int*   cnt  = (int*)carve((size_t)n * sizeof(int));          // reused as cursor
    int*   off  = (int*)carve((size_t)(n + 1) * sizeof(int));
    int*   bsum = (int*)carve(256 * sizeof(int));
    float* dinv = (float*)carve((size_t)n * sizeof(float));
    int*   esrc = (int*)carve((size_t)E * sizeof(int));
    float* h1p  = (float*)carve((size_t)n * 64 * sizeof(float));
    float* h2p  = (float*)carve((size_t)n * 32 * sizeof(float)); // no alias: fused kernel

    const int B = 256;
    const int gN = (n + B - 1) / B;
    const int gE = (E + B - 1) / B;
    const int nb = (n + 1023) / 1024;

    // CSR build + dinv
    k_zero_i<<<gN, B, 0, stream>>>(cnt, n);
    k_hist<<<gE, B, 0, stream>>>(dst, cnt, E);
    k_scan1<<<nb, B, 0, stream>>>(cnt, off, bsum, dinv, n);
    k_scan2<<<1, B, 0, stream>>>(bsum, nb);
    k_scan3<<<gN, B, 0, stream>>>(off, cnt, bsum, n, E);  // cnt becomes cursor
    k_fill<<<gE, B, 0, stream>>>(src, dst, cnt, esrc, E);

    // layer 1 transform
    k_gemm1<<<(n + 31) / 32, 128, 0, stream>>>(x, W1, dinv, h1p, n);

    // fused: aggregate layer 1 + relu + layer-2 transform
    k_agg1gemm2<<<2048, B, 0, stream>>>(h1p, off, esrc, dinv, b1, W2, h2p, n);

    // final aggregation + bias -> out
    k_agg2<<<(n + 3) / 4, B, 0, stream>>>(h2p, off, esrc, dinv, b2, out, n);
}

// Round 4
// 347.795 us; speedup vs baseline: 2.2091x; 1.4032x over previous
//
#include <hip/hip_runtime.h>

typedef unsigned int  u32;
typedef unsigned short u16;

__device__ __forceinline__ u16 f2b(float f) {
    u32 u = __float_as_uint(f);
    u += 0x7FFFu + ((u >> 16) & 1u);   // round-to-nearest-even
    return (u16)(u >> 16);
}
__device__ __forceinline__ float b2f_lo(u32 v) { return __uint_as_float(v << 16); }
__device__ __forceinline__ float b2f_hi(u32 v) { return __uint_as_float(v & 0xFFFF0000u); }
__device__ __forceinline__ u32 pack2(float a, float b) {
    return (u32)f2b(a) | ((u32)f2b(b) << 16);
}

// ---------------- CSR build ----------------

__global__ void k_hist(const int* __restrict__ dst, int* __restrict__ cnt, int E) {
    int i = blockIdx.x * blockDim.x + threadIdx.x;
    if (i < E) atomicAdd(&cnt[dst[i]], 1);
}

// block scans 1024 elements (256 thr x 4); exclusive scan + block sum + dinv
__global__ __launch_bounds__(256) void k_scan1(const int* __restrict__ cnt,
                                               int* __restrict__ out,
                                               int* __restrict__ bsum,
                                               float* __restrict__ dinv, int n) {
    __shared__ int sh[256];
    int t = threadIdx.x;
    int base = blockIdx.x * 1024 + t * 4;
    int v0 = base + 0 < n ? cnt[base + 0] : 0;
    int v1 = base + 1 < n ? cnt[base + 1] : 0;
    int v2 = base + 2 < n ? cnt[base + 2] : 0;
    int v3 = base + 3 < n ? cnt[base + 3] : 0;
    if (base + 0 < n) dinv[base + 0] = rsqrtf((float)(v0 + 1));
    if (base + 1 < n) dinv[base + 1] = rsqrtf((float)(v1 + 1));
    if (base + 2 < n) dinv[base + 2] = rsqrtf((float)(v2 + 1));
    if (base + 3 < n) dinv[base + 3] = rsqrtf((float)(v3 + 1));
    int s = v0 + v1 + v2 + v3;
    sh[t] = s;
    __syncthreads();
    for (int d = 1; d < 256; d <<= 1) {
        int x = (t >= d) ? sh[t - d] : 0;
        __syncthreads();
        sh[t] += x;
        __syncthreads();
    }
    int excl = sh[t] - s;
    if (base + 0 < n) out[base + 0] = excl;
    if (base + 1 < n) out[base + 1] = excl + v0;
    if (base + 2 < n) out[base + 2] = excl + v0 + v1;
    if (base + 3 < n) out[base + 3] = excl + v0 + v1 + v2;
    if (t == 255) bsum[blockIdx.x] = sh[255];
}

__global__ __launch_bounds__(256) void k_scan2(int* bsum, int nb) {
    __shared__ int sh[256];
    int t = threadIdx.x;
    int v = t < nb ? bsum[t] : 0;
    sh[t] = v;
    __syncthreads();
    for (int d = 1; d < 256; d <<= 1) {
        int x = (t >= d) ? sh[t - d] : 0;
        __syncthreads();
        sh[t] += x;
        __syncthreads();
    }
    if (t < nb) bsum[t] = sh[t] - v;  // exclusive
}

__global__ void k_scan3(int* __restrict__ off, int* __restrict__ cur,
                        const int* __restrict__ bsum, int n, int E) {
    int i = blockIdx.x * blockDim.x + threadIdx.x;
    if (i < n) {
        int v = off[i] + bsum[i >> 10];
        off[i] = v;
        cur[i] = v;
    }
    if (i == 0) off[n] = E;
}

__global__ void k_fill(const int* __restrict__ src, const int* __restrict__ dst,
                       int* __restrict__ cur, int* __restrict__ esrc, int E) {
    int i = blockIdx.x * blockDim.x + threadIdx.x;
    if (i < E) {
        int pos = atomicAdd(&cur[dst[i]], 1);
        esrc[pos] = src[i];
    }
}

// ---------------- gemm1: h1b = bf16((x @ W1) * dinv[row]) ----------------
// persistent-ish: W1 staged once per block; 64-row tiles, register prefetch.
// 256 thr, thread = 4 rows x 4 cols.

__global__ __launch_bounds__(256) void k_gemm1(const float* __restrict__ x,
                                               const float* __restrict__ W,
                                               const float* __restrict__ dinv,
                                               u16* __restrict__ h1b,
                                               int n, int ntiles) {
    __shared__ float Wl[128 * 64];     // 32 KB
    __shared__ float xl[64 * 132];     // 33.8 KB, pad 132
    int tid = threadIdx.x;
    for (int f = tid * 4; f < 128 * 64; f += 1024)
        *(float4*)&Wl[f] = *(const float4*)&W[f];
    int cg = tid & 15;                 // cols cg*4..+3
    int rg = tid >> 4;                 // rows rg*4..+3

    float4 pre[8];
    {
        int rowBase = blockIdx.x * 64;
#pragma unroll
        for (int it = 0; it < 8; it++) {
            int idx = it * 256 + tid;
            int r = idx >> 5, k0 = (idx & 31) * 4;
            pre[it] = (rowBase + r < n)
                ? *(const float4*)&x[(size_t)(rowBase + r) * 128 + k0]
                : make_float4(0.f, 0.f, 0.f, 0.f);
        }
    }
    for (int t = blockIdx.x; t < ntiles; t += gridDim.x) {
        __syncthreads();               // xl free (covers Wl on first pass)
#pragma unroll
        for (int it = 0; it < 8; it++) {
            int idx = it * 256 + tid;
            int r = idx >> 5, k0 = (idx & 31) * 4;
            *(float4*)&xl[r * 132 + k0] = pre[it];
        }
        __syncthreads();
        int tn = t + gridDim.x;
        if (tn < ntiles) {             // prefetch next tile under compute
            int rowBase = tn * 64;
#pragma unroll
            for (int it = 0; it < 8; it++) {
                int idx = it * 256 + tid;
                int r = idx >> 5, k0 = (idx & 31) * 4;
                pre[it] = (rowBase + r < n)
                    ? *(const float4*)&x[(size_t)(rowBase + r) * 128 + k0]
                    : make_float4(0.f, 0.f, 0.f, 0.f);
            }
        }
        float acc[4][4] = {};
        const float* wp  = &Wl[cg * 4];
        const float* xr0 = &xl[(rg * 4 + 0) * 132];
        const float* xr1 = &xl[(rg * 4 + 1) * 132];
        const float* xr2 = &xl[(rg * 4 + 2) * 132];
        const float* xr3 = &xl[(rg * 4 + 3) * 132];
#pragma unroll 4
        for (int k = 0; k < 128; k++) {
            float4 wv = *(const float4*)&wp[k * 64];
            float a0 = xr0[k], a1 = xr1[k], a2 = xr2[k], a3 = xr3[k];
            acc[0][0] += a0 * wv.x; acc[0][1] += a0 * wv.y; acc[0][2] += a0 * wv.z; acc[0][3] += a0 * wv.w;
            acc[1][0] += a1 * wv.x; acc[1][1] += a1 * wv.y; acc[1][2] += a1 * wv.z; acc[1][3] += a1 * wv.w;
            acc[2][0] += a2 * wv.x; acc[2][1] += a2 * wv.y; acc[2][2] += a2 * wv.z; acc[2][3] += a2 * wv.w;
            acc[3][0] += a3 * wv.x; acc[3][1] += a3 * wv.y; acc[3][2] += a3 * wv.z; acc[3][3] += a3 * wv.w;
        }
        int rowBase = t * 64;
#pragma unroll
        for (int i = 0; i < 4; i++) {
            int row = rowBase + rg * 4 + i;
            if (row < n) {
                float dv = dinv[row];
                uint2 o;
                o.x = pack2(acc[i][0] * dv, acc[i][1] * dv);
                o.y = pack2(acc[i][2] * dv, acc[i][3] * dv);
                *(uint2*)&h1b[(size_t)row * 64 + cg * 4] = o;
            }
        }
    }
}

// ---------------- fused agg1 + relu + gemm2 (bf16 gathers) ----------------
// wave per node; half-wave per edge (lane = ch pair), 4 edges in flight.

__global__ __launch_bounds__(256) void k_agg1gemm2(const u16* __restrict__ h1b,
                                                   const int* __restrict__ off,
                                                   const int* __restrict__ esrc,
                                                   const float* __restrict__ dinv,
                                                   const float* __restrict__ b1,
                                                   const float* __restrict__ W2,
                                                   u16* __restrict__ h2b, int n) {
    __shared__ float aggL[4][64];
    int warp = threadIdx.x >> 6, lane = threadIdx.x & 63;
    int half = lane >> 5, c2 = lane & 31;      // channels 2c2, 2c2+1
    float w2r[32];
#pragma unroll
    for (int kk = 0; kk < 32; kk++) w2r[kk] = W2[(half * 32 + kk) * 32 + c2];
    float2 bb = *(const float2*)&b1[2 * c2];
    int nwaves = (gridDim.x * blockDim.x) >> 6;
    for (int wid = (int)((blockIdx.x * blockDim.x + threadIdx.x) >> 6); wid < n;
         wid += nwaves) {
        int e0 = off[wid], e1 = off[wid + 1];
        float a0 = 0.f, a1 = 0.f, a2 = 0.f, a3 = 0.f;
        if (half == 0) {  // self-loop
            u32 v = *(const u32*)&h1b[(size_t)wid * 64 + 2 * c2];
            a0 += b2f_lo(v); a1 += b2f_hi(v);
        }
        int e = e0 + half;
        for (; e + 2 < e1; e += 4) {
            int s0 = esrc[e], s1 = esrc[e + 2];
            u32 v0 = *(const u32*)&h1b[(size_t)s0 * 64 + 2 * c2];
            u32 v1 = *(const u32*)&h1b[(size_t)s1 * 64 + 2 * c2];
            a0 += b2f_lo(v0); a1 += b2f_hi(v0);
            a2 += b2f_lo(v1); a3 += b2f_hi(v1);
        }
        if (e < e1) {
            int s = esrc[e];
            u32 v = *(const u32*)&h1b[(size_t)s * 64 + 2 * c2];
            a0 += b2f_lo(v); a1 += b2f_hi(v);
        }
        a0 += a2; a1 += a3;
        a0 += __shfl_xor(a0, 32);
        a1 += __shfl_xor(a1, 32);
        float dv = dinv[wid];
        a0 = a0 * dv + bb.x; a1 = a1 * dv + bb.y;
        a0 = a0 > 0.f ? a0 : 0.f;
        a1 = a1 > 0.f ? a1 : 0.f;
        if (half == 0) *(float2*)&aggL[warp][2 * c2] = make_float2(a0, a1);
        asm volatile("s_waitcnt lgkmcnt(0)" ::: "memory");  // wave-internal sync
        float acc = 0.f;
#pragma unroll
        for (int kk = 0; kk < 32; kk += 4) {
            float4 av = *(const float4*)&aggL[warp][half * 32 + kk];
            acc += av.x * w2r[kk] + av.y * w2r[kk + 1] + av.z * w2r[kk + 2] + av.w * w2r[kk + 3];
        }
        acc += __shfl_xor(acc, 32);
        if (half == 0) h2b[(size_t)wid * 32 + c2] = f2b(acc * dv);
    }
}

// ---------------- final aggregation -> out (bf16 gathers) ----------------
// wave per node; quarter-wave per edge (lane = ch pair).

__global__ __launch_bounds__(256) void k_agg2(const u16* __restrict__ h2b,
                                              const int* __restrict__ off,
                                              const int* __restrict__ esrc,
                                              const float* __restrict__ dinv,
                                              const float* __restrict__ b2,
                                              float* __restrict__ out, int n) {
    int wid = (int)((blockIdx.x * blockDim.x + threadIdx.x) >> 6);
    int lane = threadIdx.x & 63;
    int g = lane >> 4, c2 = lane & 15;   // channels 2c2, 2c2+1
    if (wid >= n) return;
    int e0 = off[wid], e1 = off[wid + 1];
    float a0 = 0.f, a1 = 0.f, a2 = 0.f, a3 = 0.f;
    int e = e0 + g;
    for (; e + 4 < e1; e += 8) {
        int s0 = esrc[e], s1 = esrc[e + 4];
        u32 v0 = *(const u32*)&h2b[(size_t)s0 * 32 + 2 * c2];
        u32 v1 = *(const u32*)&h2b[(size_t)s1 * 32 + 2 * c2];
        a0 += b2f_lo(v0); a1 += b2f_hi(v0);
        a2 += b2f_lo(v1); a3 += b2f_hi(v1);
    }
    if (e < e1) {
        int s = esrc[e];
        u32 v = *(const u32*)&h2b[(size_t)s * 32 + 2 * c2];
        a0 += b2f_lo(v); a1 += b2f_hi(v);
    }
    a0 += a2; a1 += a3;
    a0 += __shfl_xor(a0, 16); a0 += __shfl_xor(a0, 32);
    a1 += __shfl_xor(a1, 16); a1 += __shfl_xor(a1, 32);
    if (g == 0) {
        u32 v = *(const u32*)&h2b[(size_t)wid * 32 + 2 * c2];  // self-loop
        a0 += b2f_lo(v); a1 += b2f_hi(v);
        float dv = dinv[wid];
        float2 o = make_float2(a0 * dv + b2[2 * c2], a1 * dv + b2[2 * c2 + 1]);
        *(float2*)&out[(size_t)wid * 32 + 2 * c2] = o;
    }
}

// ---------------- launch ----------------

extern "C" void kernel_launch(void* const* d_in, const int* in_sizes, int n_in,
                              void* d_out, int out_size, void* d_ws, size_t ws_size,
                              hipStream_t stream) {
    const float* x  = (const float*)d_in[0];
    const int*   ei = (const int*)d_in[1];
    const float* W1 = (const float*)d_in[2];
    const float* b1 = (const float*)d_in[3];
    const float* W2 = (const float*)d_in[4];
    const float* b2 = (const float*)d_in[5];
    float* out = (float*)d_out;

    const int n = in_sizes[0] / 128;
    const int E = in_sizes[1] / 2;
    const int* src = ei;
    const int* dst = ei + E;

    char* ws = (char*)d_ws;
    size_t woff = 0;
    auto carve = [&](size_t bytes) {
        void* p = ws + woff;
        woff += (bytes + 255) & ~(size_t)255;
        return p;
    };
    int*   cnt  = (int*)carve((size_t)n * sizeof(int));          // reused as cursor
    int*   off  = (int*)carve((size_t)(n + 1) * sizeof(int));
    int*   bsum = (int*)carve(256 * sizeof(int));
    float* dinv = (float*)carve((size_t)n * sizeof(float));
    int*   esrc = (int*)carve((size_t)E * sizeof(int));
    u16*   h1b  = (u16*)carve((size_t)n * 64 * sizeof(u16));
    u16*   h2b  = (u16*)carve((size_t)n * 32 * sizeof(u16));

    const int B = 256;
    const int gN = (n + B - 1) / B;
    const int gE = (E + B - 1) / B;
    const int nb = (n + 1023) / 1024;
    const int ntiles = (n + 63) / 64;

    // CSR build + dinv
    hipMemsetAsync(cnt, 0, (size_t)n * sizeof(int), stream);
    k_hist<<<gE, B, 0, stream>>>(dst, cnt, E);
    k_scan1<<<nb, B, 0, stream>>>(cnt, off, bsum, dinv, n);
    k_scan2<<<1, B, 0, stream>>>(bsum, nb);
    k_scan3<<<gN, B, 0, stream>>>(off, cnt, bsum, n, E);  // cnt becomes cursor
    k_fill<<<gE, B, 0, stream>>>(src, dst, cnt, esrc, E);

    // layer 1 transform (bf16 out)
    int g1 = ntiles < 521 ? ntiles : 521;
    k_gemm1<<<g1, B, 0, stream>>>(x, W1, dinv, h1b, n, ntiles);

    // fused: aggregate layer 1 + relu + layer-2 transform (bf16 out)
    k_agg1gemm2<<<2048, B, 0, stream>>>(h1b, off, esrc, dinv, b1, W2, h2b, n);

    // final aggregation + bias -> out (fp32)
    k_agg2<<<(n + 3) / 4, B, 0, stream>>>(h2b, off, esrc, dinv, b2, out, n);
}

// Round 5
// 211.163 us; speedup vs baseline: 3.6385x; 1.6470x over previous
//
#include <hip/hip_runtime.h>

typedef unsigned int   u32;
typedef unsigned short u16;

__device__ __forceinline__ u16 f2b(float f) {
    u32 u = __float_as_uint(f);
    u += 0x7FFFu + ((u >> 16) & 1u);   // round-to-nearest-even
    return (u16)(u >> 16);
}
__device__ __forceinline__ float b2f_lo(u32 v) { return __uint_as_float(v << 16); }
__device__ __forceinline__ float b2f_hi(u32 v) { return __uint_as_float(v & 0xFFFF0000u); }
__device__ __forceinline__ u32 pack2(float a, float b) {
    return (u32)f2b(a) | ((u32)f2b(b) << 16);
}

#define BSHIFT 8                      // 256 nodes per bucket
#define BIN_CHUNK 4096                // edges per k_bin block

// ---------------- bucketed CSR build ----------------

// A1: global bucket histogram via per-block LDS histogram
__global__ __launch_bounds__(256) void k_bhist(const int* __restrict__ dst,
                                               int* __restrict__ bcnt, int E, int NB) {
    __shared__ int lh[512];
    for (int i = threadIdx.x; i < 512; i += 256) lh[i] = 0;
    __syncthreads();
    int base = blockIdx.x * 2048 + threadIdx.x;
#pragma unroll
    for (int t = 0; t < 8; t++) {
        int i = base + t * 256;
        if (i < E) atomicAdd(&lh[dst[i] >> BSHIFT], 1);
    }
    __syncthreads();
    for (int i = threadIdx.x; i < NB; i += 256)
        if (lh[i]) atomicAdd(&bcnt[i], lh[i]);
}

// exclusive scan of bucket counts (NB <= 512 in one pass; carry loop for safety)
__global__ __launch_bounds__(512) void k_bscan(const int* __restrict__ bcnt,
                                               int* __restrict__ bbase,
                                               int* __restrict__ bcur, int NB, int E) {
    __shared__ int sh[512];
    __shared__ int carryS;
    int t = threadIdx.x;
    if (t == 0) carryS = 0;
    __syncthreads();
    for (int c0 = 0; c0 < NB; c0 += 512) {
        int v = (c0 + t < NB) ? bcnt[c0 + t] : 0;
        sh[t] = v;
        __syncthreads();
        for (int d = 1; d < 512; d <<= 1) {
            int x = t >= d ? sh[t - d] : 0;
            __syncthreads();
            sh[t] += x;
            __syncthreads();
        }
        int excl = sh[t] - v + carryS;
        if (c0 + t < NB) { bbase[c0 + t] = excl; bcur[c0 + t] = excl; }
        int tot = sh[511];
        __syncthreads();
        if (t == 0) carryS += tot;
        __syncthreads();
    }
    if (t == 0) bbase[NB] = E;
}

// A2: block counting-sort of 4096 edges into bucket-ordered global array.
// Writes contiguous per-bucket runs (avg ~10 edges) -> batched HBM writes.
__global__ __launch_bounds__(256) void k_bin(const int* __restrict__ src,
                                             const int* __restrict__ dst,
                                             int* __restrict__ bcur,
                                             uint2* __restrict__ binned,
                                             int E, int NB) {
    __shared__ int lh[512], ls[512], gb[512];
    __shared__ int sh[256];
    __shared__ uint2 stage[BIN_CHUNK];
    int tid = threadIdx.x;
    int base = blockIdx.x * BIN_CHUNK;
    int cnt = E - base;
    if (cnt > BIN_CHUNK) cnt = BIN_CHUNK;

    for (int i = tid; i < 512; i += 256) lh[i] = 0;
    __syncthreads();

    int d[16], s[16], r[16];
#pragma unroll
    for (int t = 0; t < 16; t++) {
        int i = base + t * 256 + tid;
        d[t] = -1;
        if (i < E) {
            d[t] = dst[i];
            s[t] = src[i];
            r[t] = atomicAdd(&lh[d[t] >> BSHIFT], 1);
        }
    }
    __syncthreads();
    // exclusive scan of lh[512] with 256 threads (pairwise)
    {
        int a0 = lh[2 * tid], a1 = lh[2 * tid + 1];
        int sum2 = a0 + a1;
        sh[tid] = sum2;
        __syncthreads();
        for (int dd = 1; dd < 256; dd <<= 1) {
            int x = tid >= dd ? sh[tid - dd] : 0;
            __syncthreads();
            sh[tid] += x;
            __syncthreads();
        }
        int excl = sh[tid] - sum2;
        ls[2 * tid] = excl;
        ls[2 * tid + 1] = excl + a0;
    }
    // reserve global slices (one atomic per non-empty bucket)
    for (int b = tid; b < NB; b += 256) {
        int c = lh[b];
        gb[b] = c ? atomicAdd(&bcur[b], c) : 0;
    }
    __syncthreads();
    // scatter to LDS staging in bucket order
#pragma unroll
    for (int t = 0; t < 16; t++) {
        if (d[t] >= 0) {
            int slot = ls[d[t] >> BSHIFT] + r[t];
            stage[slot] = make_uint2((u32)d[t], (u32)s[t]);
        }
    }
    __syncthreads();
    // write out: consecutive threads -> consecutive slots -> contiguous runs
    for (int j = tid; j < cnt; j += 256) {
        uint2 e = stage[j];
        int b = (int)(e.x >> BSHIFT);
        int addr = gb[b] + (j - ls[b]);
        binned[addr] = e;
    }
}

// B: one block per bucket -> exact CSR (off, esrc) + dinv. esrc writes land in
// an L2-resident ~16KB window (no write amplification).
__global__ __launch_bounds__(256) void k_csr(const uint2* __restrict__ binned,
                                             const int* __restrict__ bbase,
                                             float* __restrict__ dinv,
                                             int* __restrict__ off,
                                             int* __restrict__ esrc,
                                             int n, int E) {
    __shared__ int lcnt[256], lcur[256], sh[256];
    int tid = threadIdx.x;
    int b = blockIdx.x;
    int nodeBase = b << BSHIFT;
    int ebase = bbase[b];
    int ecnt = bbase[b + 1] - ebase;
    lcnt[tid] = 0;
    __syncthreads();
    for (int j = tid; j < ecnt; j += 256)
        atomicAdd(&lcnt[binned[ebase + j].x - nodeBase], 1);
    __syncthreads();
    int v = lcnt[tid];
    sh[tid] = v;
    __syncthreads();
    for (int d = 1; d < 256; d <<= 1) {
        int x = tid >= d ? sh[tid - d] : 0;
        __syncthreads();
        sh[tid] += x;
        __syncthreads();
    }
    int excl = sh[tid] - v;
    int node = nodeBase + tid;
    if (node < n) {
        off[node] = ebase + excl;
        dinv[node] = rsqrtf((float)(v + 1));
    }
    lcur[tid] = excl;
    if (b == 0 && tid == 0) off[n] = E;
    __syncthreads();
    for (int j = tid; j < ecnt; j += 256) {
        uint2 e = binned[ebase + j];
        int p = atomicAdd(&lcur[e.x - nodeBase], 1);
        esrc[ebase + p] = (int)e.y;
    }
}

// ---------------- gemm1: h1b = bf16((x @ W1) * dinv[row]) ----------------

__global__ __launch_bounds__(256) void k_gemm1(const float* __restrict__ x,
                                               const float* __restrict__ W,
                                               const float* __restrict__ dinv,
                                               u16* __restrict__ h1b,
                                               int n, int ntiles) {
    __shared__ float Wl[128 * 64];
    __shared__ float xl[64 * 132];
    int tid = threadIdx.x;
    for (int f = tid * 4; f < 128 * 64; f += 1024)
        *(float4*)&Wl[f] = *(const float4*)&W[f];
    int cg = tid & 15;
    int rg = tid >> 4;

    float4 pre[8];
    {
        int rowBase = blockIdx.x * 64;
#pragma unroll
        for (int it = 0; it < 8; it++) {
            int idx = it * 256 + tid;
            int r = idx >> 5, k0 = (idx & 31) * 4;
            pre[it] = (rowBase + r < n)
                ? *(const float4*)&x[(size_t)(rowBase + r) * 128 + k0]
                : make_float4(0.f, 0.f, 0.f, 0.f);
        }
    }
    for (int t = blockIdx.x; t < ntiles; t += gridDim.x) {
        __syncthreads();
#pragma unroll
        for (int it = 0; it < 8; it++) {
            int idx = it * 256 + tid;
            int r = idx >> 5, k0 = (idx & 31) * 4;
            *(float4*)&xl[r * 132 + k0] = pre[it];
        }
        __syncthreads();
        int tn = t + gridDim.x;
        if (tn < ntiles) {
            int rowBase = tn * 64;
#pragma unroll
            for (int it = 0; it < 8; it++) {
                int idx = it * 256 + tid;
                int r = idx >> 5, k0 = (idx & 31) * 4;
                pre[it] = (rowBase + r < n)
                    ? *(const float4*)&x[(size_t)(rowBase + r) * 128 + k0]
                    : make_float4(0.f, 0.f, 0.f, 0.f);
            }
        }
        float acc[4][4] = {};
        const float* wp  = &Wl[cg * 4];
        const float* xr0 = &xl[(rg * 4 + 0) * 132];
        const float* xr1 = &xl[(rg * 4 + 1) * 132];
        const float* xr2 = &xl[(rg * 4 + 2) * 132];
        const float* xr3 = &xl[(rg * 4 + 3) * 132];
#pragma unroll 4
        for (int k = 0; k < 128; k++) {
            float4 wv = *(const float4*)&wp[k * 64];
            float a0 = xr0[k], a1 = xr1[k], a2 = xr2[k], a3 = xr3[k];
            acc[0][0] += a0 * wv.x; acc[0][1] += a0 * wv.y; acc[0][2] += a0 * wv.z; acc[0][3] += a0 * wv.w;
            acc[1][0] += a1 * wv.x; acc[1][1] += a1 * wv.y; acc[1][2] += a1 * wv.z; acc[1][3] += a1 * wv.w;
            acc[2][0] += a2 * wv.x; acc[2][1] += a2 * wv.y; acc[2][2] += a2 * wv.z; acc[2][3] += a2 * wv.w;
            acc[3][0] += a3 * wv.x; acc[3][1] += a3 * wv.y; acc[3][2] += a3 * wv.z; acc[3][3] += a3 * wv.w;
        }
        int rowBase = t * 64;
#pragma unroll
        for (int i = 0; i < 4; i++) {
            int row = rowBase + rg * 4 + i;
            if (row < n) {
                float dv = dinv[row];
                uint2 o;
                o.x = pack2(acc[i][0] * dv, acc[i][1] * dv);
                o.y = pack2(acc[i][2] * dv, acc[i][3] * dv);
                *(uint2*)&h1b[(size_t)row * 64 + cg * 4] = o;
            }
        }
    }
}

// ---------------- fused agg1 + relu + gemm2 (bf16 gathers) ----------------

__global__ __launch_bounds__(256) void k_agg1gemm2(const u16* __restrict__ h1b,
                                                   const int* __restrict__ off,
                                                   const int* __restrict__ esrc,
                                                   const float* __restrict__ dinv,
                                                   const float* __restrict__ b1,
                                                   const float* __restrict__ W2,
                                                   u16* __restrict__ h2b, int n) {
    __shared__ float aggL[4][64];
    int warp = threadIdx.x >> 6, lane = threadIdx.x & 63;
    int half = lane >> 5, c2 = lane & 31;
    float w2r[32];
#pragma unroll
    for (int kk = 0; kk < 32; kk++) w2r[kk] = W2[(half * 32 + kk) * 32 + c2];
    float2 bb = *(const float2*)&b1[2 * c2];
    int nwaves = (gridDim.x * blockDim.x) >> 6;
    for (int wid = (int)((blockIdx.x * blockDim.x + threadIdx.x) >> 6); wid < n;
         wid += nwaves) {
        int e0 = off[wid], e1 = off[wid + 1];
        float a0 = 0.f, a1 = 0.f, a2 = 0.f, a3 = 0.f;
        if (half == 0) {
            u32 v = *(const u32*)&h1b[(size_t)wid * 64 + 2 * c2];
            a0 += b2f_lo(v); a1 += b2f_hi(v);
        }
        int e = e0 + half;
        for (; e + 2 < e1; e += 4) {
            int s0 = esrc[e], s1 = esrc[e + 2];
            u32 v0 = *(const u32*)&h1b[(size_t)s0 * 64 + 2 * c2];
            u32 v1 = *(const u32*)&h1b[(size_t)s1 * 64 + 2 * c2];
            a0 += b2f_lo(v0); a1 += b2f_hi(v0);
            a2 += b2f_lo(v1); a3 += b2f_hi(v1);
        }
        if (e < e1) {
            int s = esrc[e];
            u32 v = *(const u32*)&h1b[(size_t)s * 64 + 2 * c2];
            a0 += b2f_lo(v); a1 += b2f_hi(v);
        }
        a0 += a2; a1 += a3;
        a0 += __shfl_xor(a0, 32);
        a1 += __shfl_xor(a1, 32);
        float dv = dinv[wid];
        a0 = a0 * dv + bb.x; a1 = a1 * dv + bb.y;
        a0 = a0 > 0.f ? a0 : 0.f;
        a1 = a1 > 0.f ? a1 : 0.f;
        if (half == 0) *(float2*)&aggL[warp][2 * c2] = make_float2(a0, a1);
        asm volatile("s_waitcnt lgkmcnt(0)" ::: "memory");
        float acc = 0.f;
#pragma unroll
        for (int kk = 0; kk < 32; kk += 4) {
            float4 av = *(const float4*)&aggL[warp][half * 32 + kk];
            acc += av.x * w2r[kk] + av.y * w2r[kk + 1] + av.z * w2r[kk + 2] + av.w * w2r[kk + 3];
        }
        acc += __shfl_xor(acc, 32);
        if (half == 0) h2b[(size_t)wid * 32 + c2] = f2b(acc * dv);
    }
}

// ---------------- final aggregation -> out (bf16 gathers) ----------------

__global__ __launch_bounds__(256) void k_agg2(const u16* __restrict__ h2b,
                                              const int* __restrict__ off,
                                              const int* __restrict__ esrc,
                                              const float* __restrict__ dinv,
                                              const float* __restrict__ b2,
                                              float* __restrict__ out, int n) {
    int wid = (int)((blockIdx.x * blockDim.x + threadIdx.x) >> 6);
    int lane = threadIdx.x & 63;
    int g = lane >> 4, c2 = lane & 15;
    if (wid >= n) return;
    int e0 = off[wid], e1 = off[wid + 1];
    float a0 = 0.f, a1 = 0.f, a2 = 0.f, a3 = 0.f;
    int e = e0 + g;
    for (; e + 4 < e1; e += 8) {
        int s0 = esrc[e], s1 = esrc[e + 4];
        u32 v0 = *(const u32*)&h2b[(size_t)s0 * 32 + 2 * c2];
        u32 v1 = *(const u32*)&h2b[(size_t)s1 * 32 + 2 * c2];
        a0 += b2f_lo(v0); a1 += b2f_hi(v0);
        a2 += b2f_lo(v1); a3 += b2f_hi(v1);
    }
    if (e < e1) {
        int s = esrc[e];
        u32 v = *(const u32*)&h2b[(size_t)s * 32 + 2 * c2];
        a0 += b2f_lo(v); a1 += b2f_hi(v);
    }
    a0 += a2; a1 += a3;
    a0 += __shfl_xor(a0, 16); a0 += __shfl_xor(a0, 32);
    a1 += __shfl_xor(a1, 16); a1 += __shfl_xor(a1, 32);
    if (g == 0) {
        u32 v = *(const u32*)&h2b[(size_t)wid * 32 + 2 * c2];
        a0 += b2f_lo(v); a1 += b2f_hi(v);
        float dv = dinv[wid];
        float2 o = make_float2(a0 * dv + b2[2 * c2], a1 * dv + b2[2 * c2 + 1]);
        *(float2*)&out[(size_t)wid * 32 + 2 * c2] = o;
    }
}

// ---------------- launch ----------------

extern "C" void kernel_launch(void* const* d_in, const int* in_sizes, int n_in,
                              void* d_out, int out_size, void* d_ws, size_t ws_size,
                              hipStream_t stream) {
    const float* x  = (const float*)d_in[0];
    const int*   ei = (const int*)d_in[1];
    const float* W1 = (const float*)d_in[2];
    const float* b1 = (const float*)d_in[3];
    const float* W2 = (const float*)d_in[4];
    const float* b2 = (const float*)d_in[5];
    float* out = (float*)d_out;

    const int n = in_sizes[0] / 128;
    const int E = in_sizes[1] / 2;
    const int* src = ei;
    const int* dst = ei + E;
    const int NB = (n + 255) >> BSHIFT;

    char* ws = (char*)d_ws;
    size_t woff = 0;
    auto carve = [&](size_t bytes) {
        void* p = ws + woff;
        woff += (bytes + 255) & ~(size_t)255;
        return p;
    };
    int*   bcnt  = (int*)carve((size_t)(NB + 1) * sizeof(int));
    int*   bbase = (int*)carve((size_t)(NB + 1) * sizeof(int));
    int*   bcur  = (int*)carve((size_t)NB * sizeof(int));
    uint2* binned= (uint2*)carve((size_t)E * sizeof(uint2));
    int*   off   = (int*)carve((size_t)(n + 1) * sizeof(int));
    float* dinv  = (float*)carve((size_t)n * sizeof(float));
    int*   esrc  = (int*)carve((size_t)E * sizeof(int));
    u16*   h1b   = (u16*)carve((size_t)n * 64 * sizeof(u16));
    u16*   h2b   = (u16*)carve((size_t)n * 32 * sizeof(u16));

    const int B = 256;
    const int ntiles = (n + 63) / 64;

    // bucketed CSR build (produces off, esrc, dinv)
    hipMemsetAsync(bcnt, 0, (size_t)(NB + 1) * sizeof(int), stream);
    k_bhist<<<(E + 2047) / 2048, B, 0, stream>>>(dst, bcnt, E, NB);
    k_bscan<<<1, 512, 0, stream>>>(bcnt, bbase, bcur, NB, E);
    k_bin<<<(E + BIN_CHUNK - 1) / BIN_CHUNK, B, 0, stream>>>(src, dst, bcur, binned, E, NB);
    k_csr<<<NB, B, 0, stream>>>(binned, bbase, dinv, off, esrc, n, E);

    // layer 1 transform (bf16 out)
    int g1 = ntiles < 521 ? ntiles : 521;
    k_gemm1<<<g1, B, 0, stream>>>(x, W1, dinv, h1b, n, ntiles);

    // fused: aggregate layer 1 + relu + layer-2 transform (bf16 out)
    k_agg1gemm2<<<2048, B, 0, stream>>>(h1b, off, esrc, dinv, b1, W2, h2b, n);

    // final aggregation + bias -> out (fp32)
    k_agg2<<<(n + 3) / 4, B, 0, stream>>>(h2b, off, esrc, dinv, b2, out, n);
}

// Round 6
// 198.760 us; speedup vs baseline: 3.8655x; 1.0624x over previous
//
#include <hip/hip_runtime.h>

typedef unsigned int   u32;
typedef unsigned short u16;
typedef __attribute__((ext_vector_type(8))) short bf16x8;
typedef __attribute__((ext_vector_type(4))) float f32x4;

__device__ __forceinline__ u16 f2b(float f) {
    u32 u = __float_as_uint(f);
    u += 0x7FFFu + ((u >> 16) & 1u);   // round-to-nearest-even
    return (u16)(u >> 16);
}
__device__ __forceinline__ float b2f_lo(u32 v) { return __uint_as_float(v << 16); }
__device__ __forceinline__ float b2f_hi(u32 v) { return __uint_as_float(v & 0xFFFF0000u); }
__device__ __forceinline__ u32 pack2(float a, float b) {
    return (u32)f2b(a) | ((u32)f2b(b) << 16);
}

#define BSHIFT 8                      // 256 nodes per bucket
#define BIN_CHUNK 4096                // edges per k_bin block
#define CAP_MAX 8192                  // max padded bucket capacity (LDS stage bound)

// ---------------- bucketed edge binning (padded regions, no scan) ----------------
// Packs each edge as (dstLocal<<24)|src into bucket-ordered padded array.

__global__ __launch_bounds__(256) void k_bin(const int* __restrict__ src,
                                             const int* __restrict__ dst,
                                             int* __restrict__ bcnt,
                                             u32* __restrict__ binned,
                                             int E, int NB, int CAP) {
    __shared__ int lh[512], ls[512], gb[512], sh[256];
    __shared__ u32 stage[BIN_CHUNK];
    __shared__ u16 sbuck[BIN_CHUNK];
    int tid = threadIdx.x;
    int base = blockIdx.x * BIN_CHUNK;
    int cnt = E - base;
    if (cnt > BIN_CHUNK) cnt = BIN_CHUNK;

    for (int i = tid; i < 512; i += 256) lh[i] = 0;
    __syncthreads();

    int bk[16], r[16];
    u32 key[16];
#pragma unroll
    for (int t = 0; t < 16; t++) {
        int i = base + t * 256 + tid;
        bk[t] = -1;
        if (i < E) {
            int dv = dst[i];
            bk[t] = dv >> BSHIFT;
            key[t] = ((u32)(dv & 255) << 24) | (u32)src[i];
            r[t] = atomicAdd(&lh[bk[t]], 1);
        }
    }
    __syncthreads();
    // exclusive scan of lh[512] with 256 threads (pairwise)
    {
        int a0 = lh[2 * tid], a1 = lh[2 * tid + 1];
        int sum2 = a0 + a1;
        sh[tid] = sum2;
        __syncthreads();
        for (int dd = 1; dd < 256; dd <<= 1) {
            int x = tid >= dd ? sh[tid - dd] : 0;
            __syncthreads();
            sh[tid] += x;
            __syncthreads();
        }
        int excl = sh[tid] - sum2;
        ls[2 * tid] = excl;
        ls[2 * tid + 1] = excl + a0;
    }
    // reserve padded-region slices (one global atomic per non-empty bucket)
    for (int b = tid; b < NB; b += 256) {
        int c = lh[b];
        gb[b] = c ? atomicAdd(&bcnt[b], c) : 0;
    }
    __syncthreads();
    // scatter to LDS staging in bucket order
#pragma unroll
    for (int t = 0; t < 16; t++) {
        if (bk[t] >= 0) {
            int slot = ls[bk[t]] + r[t];
            stage[slot] = key[t];
            sbuck[slot] = (u16)bk[t];
        }
    }
    __syncthreads();
    // write out contiguous per-bucket runs
    for (int j = tid; j < cnt; j += 256) {
        u32 e = stage[j];
        int b = sbuck[j];
        int p = gb[b] + (j - ls[b]);
        if (p < CAP) binned[(size_t)b * CAP + p] = e;
    }
}

// one block per bucket: exact per-node CSR slices (offse) + dinv + esrc
__global__ __launch_bounds__(256) void k_csr(const u32* __restrict__ binned,
                                             const int* __restrict__ bcnt,
                                             float* __restrict__ dinv,
                                             int2* __restrict__ offse,
                                             int* __restrict__ esrc,
                                             int n, int CAP) {
    __shared__ int lcnt[256], lcur[256], sh[256];
    __shared__ u32 stagec[CAP_MAX];
    int tid = threadIdx.x;
    int b = blockIdx.x;
    size_t base = (size_t)b * CAP;
    int ecnt = bcnt[b];
    if (ecnt > CAP) ecnt = CAP;
    lcnt[tid] = 0;
    __syncthreads();
    for (int j = tid; j < ecnt; j += 256) {
        u32 e = binned[base + j];
        stagec[j] = e;
        atomicAdd(&lcnt[e >> 24], 1);
    }
    __syncthreads();
    int v = lcnt[tid];
    sh[tid] = v;
    __syncthreads();
    for (int d = 1; d < 256; d <<= 1) {
        int x = tid >= d ? sh[tid - d] : 0;
        __syncthreads();
        sh[tid] += x;
        __syncthreads();
    }
    int excl = sh[tid] - v;
    int node = (b << BSHIFT) + tid;
    if (node < n) {
        offse[node] = make_int2((int)base + excl, (int)base + excl + v);
        dinv[node] = rsqrtf((float)(v + 1));
    }
    lcur[tid] = excl;
    __syncthreads();
    for (int j = tid; j < ecnt; j += 256) {
        u32 e = stagec[j];
        int p = atomicAdd(&lcur[e >> 24], 1);
        esrc[base + p] = (int)(e & 0xFFFFFFu);
    }
}

// ---------------- W1 fragment pre-pack (bf16 MFMA B-fragments) ----------------
// Wpack[(ct*4+ks)*64 + lane] = 8 bf16: W1[ks*32 + (lane>>4)*8 + j][ct*16 + (lane&15)]

__global__ void k_prepW(const float* __restrict__ W1, bf16x8* __restrict__ Wpack) {
    int lane = threadIdx.x;   // 64 threads
#pragma unroll
    for (int ct = 0; ct < 4; ct++) {
#pragma unroll
        for (int ks = 0; ks < 4; ks++) {
            bf16x8 h;
#pragma unroll
            for (int j = 0; j < 8; j++) {
                int k = ks * 32 + ((lane >> 4) << 3) + j;
                int col = ct * 16 + (lane & 15);
                h[j] = (short)f2b(W1[k * 64 + col]);
            }
            Wpack[(ct * 4 + ks) * 64 + lane] = h;
        }
    }
}

// ---------------- gemm1 via MFMA: h1b = bf16((x @ W1) * dinv[row]) ----------------
// one wave per 16-row tile; A from global (fp32->bf16 in-register), B in VGPRs.

__global__ __launch_bounds__(256) void k_gemm1_mfma(const float* __restrict__ x,
                                                    const bf16x8* __restrict__ Wpack,
                                                    const float* __restrict__ dinv,
                                                    u16* __restrict__ h1b,
                                                    int n, int ntiles) {
    int gwave = (int)((blockIdx.x * blockDim.x + threadIdx.x) >> 6);
    int lane = threadIdx.x & 63;
    if (gwave >= ntiles) return;
    int rowBase = gwave * 16;

    bf16x8 bfr[16];
#pragma unroll
    for (int f = 0; f < 16; f++) bfr[f] = Wpack[f * 64 + lane];

    f32x4 acc[4];
#pragma unroll
    for (int ct = 0; ct < 4; ct++) acc[ct] = (f32x4){0.f, 0.f, 0.f, 0.f};

    int r0 = rowBase + (lane & 15);
    if (r0 >= n) r0 = n - 1;                 // clamp: D row i only uses A row i
    const float* xr = x + (size_t)r0 * 128 + ((lane >> 4) << 3);

#pragma unroll
    for (int ks = 0; ks < 4; ks++) {
        float4 p0 = *(const float4*)(xr + ks * 32);
        float4 p1 = *(const float4*)(xr + ks * 32 + 4);
        bf16x8 a;
        a[0] = (short)f2b(p0.x); a[1] = (short)f2b(p0.y);
        a[2] = (short)f2b(p0.z); a[3] = (short)f2b(p0.w);
        a[4] = (short)f2b(p1.x); a[5] = (short)f2b(p1.y);
        a[6] = (short)f2b(p1.z); a[7] = (short)f2b(p1.w);
#pragma unroll
        for (int ct = 0; ct < 4; ct++)
            acc[ct] = __builtin_amdgcn_mfma_f32_16x16x32_bf16(a, bfr[ct * 4 + ks], acc[ct], 0, 0, 0);
    }

    // C/D layout: col = lane&15, row = (lane>>4)*4 + r  [m89-verified]
    int rbase = rowBase + ((lane >> 4) << 2);
#pragma unroll
    for (int r = 0; r < 4; r++) {
        int row = rbase + r;
        float dv = (row < n) ? dinv[row] : 0.f;
#pragma unroll
        for (int ct = 0; ct < 4; ct++) {
            float o = acc[ct][r] * dv;
            float onb = __shfl_xor(o, 1);    // neighbor col
            if (!(lane & 1) && row < n) {
                *(u32*)&h1b[(size_t)row * 64 + ct * 16 + (lane & 15)] = pack2(o, onb);
            }
        }
    }
}

// ---------------- fused agg1 + relu + gemm2 (bf16 gathers, 4-slot unroll) ----------------

__global__ __launch_bounds__(256) void k_agg1gemm2(const u16* __restrict__ h1b,
                                                   const int2* __restrict__ offse,
                                                   const int* __restrict__ esrc,
                                                   const float* __restrict__ dinv,
                                                   const float* __restrict__ b1,
                                                   const float* __restrict__ W2,
                                                   u16* __restrict__ h2b, int n) {
    __shared__ float aggL[4][64];
    int warp = threadIdx.x >> 6, lane = threadIdx.x & 63;
    int half = lane >> 5, c2 = lane & 31;
    float w2r[32];
#pragma unroll
    for (int kk = 0; kk < 32; kk++) w2r[kk] = W2[(half * 32 + kk) * 32 + c2];
    float2 bb = *(const float2*)&b1[2 * c2];
    int nwaves = (gridDim.x * blockDim.x) >> 6;
    for (int wid = (int)((blockIdx.x * blockDim.x + threadIdx.x) >> 6); wid < n;
         wid += nwaves) {
        int2 ov = offse[wid];
        int en = ov.y;
        float a0 = 0.f, a1 = 0.f, a2 = 0.f, a3 = 0.f;
        float a4 = 0.f, a5 = 0.f, a6 = 0.f, a7 = 0.f;
        if (half == 0) {  // self-loop
            u32 v = *(const u32*)&h1b[(size_t)wid * 64 + 2 * c2];
            a0 += b2f_lo(v); a1 += b2f_hi(v);
        }
        int e = ov.x + half;
        for (; e + 6 < en; e += 8) {         // 4 slots per half-wave in flight
            int s0 = esrc[e], s1 = esrc[e + 2], s2 = esrc[e + 4], s3 = esrc[e + 6];
            u32 v0 = *(const u32*)&h1b[(size_t)s0 * 64 + 2 * c2];
            u32 v1 = *(const u32*)&h1b[(size_t)s1 * 64 + 2 * c2];
            u32 v2 = *(const u32*)&h1b[(size_t)s2 * 64 + 2 * c2];
            u32 v3 = *(const u32*)&h1b[(size_t)s3 * 64 + 2 * c2];
            a0 += b2f_lo(v0); a1 += b2f_hi(v0);
            a2 += b2f_lo(v1); a3 += b2f_hi(v1);
            a4 += b2f_lo(v2); a5 += b2f_hi(v2);
            a6 += b2f_lo(v3); a7 += b2f_hi(v3);
        }
        for (; e < en; e += 2) {
            int s = esrc[e];
            u32 v = *(const u32*)&h1b[(size_t)s * 64 + 2 * c2];
            a0 += b2f_lo(v); a1 += b2f_hi(v);
        }
        a0 += a2 + a4 + a6;
        a1 += a3 + a5 + a7;
        a0 += __shfl_xor(a0, 32);
        a1 += __shfl_xor(a1, 32);
        float dv = dinv[wid];
        a0 = a0 * dv + bb.x; a1 = a1 * dv + bb.y;
        a0 = a0 > 0.f ? a0 : 0.f;
        a1 = a1 > 0.f ? a1 : 0.f;
        if (half == 0) *(float2*)&aggL[warp][2 * c2] = make_float2(a0, a1);
        asm volatile("s_waitcnt lgkmcnt(0)" ::: "memory");
        float acc = 0.f;
#pragma unroll
        for (int kk = 0; kk < 32; kk += 4) {
            float4 av = *(const float4*)&aggL[warp][half * 32 + kk];
            acc += av.x * w2r[kk] + av.y * w2r[kk + 1] + av.z * w2r[kk + 2] + av.w * w2r[kk + 3];
        }
        acc += __shfl_xor(acc, 32);
        if (half == 0) h2b[(size_t)wid * 32 + c2] = f2b(acc * dv);
    }
}

// ---------------- final aggregation -> out (bf16 gathers, 4-slot unroll) ----------------

__global__ __launch_bounds__(256) void k_agg2(const u16* __restrict__ h2b,
                                              const int2* __restrict__ offse,
                                              const int* __restrict__ esrc,
                                              const float* __restrict__ dinv,
                                              const float* __restrict__ b2,
                                              float* __restrict__ out, int n) {
    int wid = (int)((blockIdx.x * blockDim.x + threadIdx.x) >> 6);
    int lane = threadIdx.x & 63;
    int g = lane >> 4, c2 = lane & 15;
    if (wid >= n) return;
    int2 ov = offse[wid];
    int en = ov.y;
    float a0 = 0.f, a1 = 0.f, a2 = 0.f, a3 = 0.f;
    float a4 = 0.f, a5 = 0.f, a6 = 0.f, a7 = 0.f;
    int e = ov.x + g;
    for (; e + 12 < en; e += 16) {           // 4 slots per quarter-wave in flight
        int s0 = esrc[e], s1 = esrc[e + 4], s2 = esrc[e + 8], s3 = esrc[e + 12];
        u32 v0 = *(const u32*)&h2b[(size_t)s0 * 32 + 2 * c2];
        u32 v1 = *(const u32*)&h2b[(size_t)s1 * 32 + 2 * c2];
        u32 v2 = *(const u32*)&h2b[(size_t)s2 * 32 + 2 * c2];
        u32 v3 = *(const u32*)&h2b[(size_t)s3 * 32 + 2 * c2];
        a0 += b2f_lo(v0); a1 += b2f_hi(v0);
        a2 += b2f_lo(v1); a3 += b2f_hi(v1);
        a4 += b2f_lo(v2); a5 += b2f_hi(v2);
        a6 += b2f_lo(v3); a7 += b2f_hi(v3);
    }
    for (; e < en; e += 4) {
        int s = esrc[e];
        u32 v = *(const u32*)&h2b[(size_t)s * 32 + 2 * c2];
        a0 += b2f_lo(v); a1 += b2f_hi(v);
    }
    a0 += a2 + a4 + a6;
    a1 += a3 + a5 + a7;
    a0 += __shfl_xor(a0, 16); a0 += __shfl_xor(a0, 32);
    a1 += __shfl_xor(a1, 16); a1 += __shfl_xor(a1, 32);
    if (g == 0) {
        u32 v = *(const u32*)&h2b[(size_t)wid * 32 + 2 * c2];  // self-loop
        a0 += b2f_lo(v); a1 += b2f_hi(v);
        float dv = dinv[wid];
        float2 o = make_float2(a0 * dv + b2[2 * c2], a1 * dv + b2[2 * c2 + 1]);
        *(float2*)&out[(size_t)wid * 32 + 2 * c2] = o;
    }
}

// ---------------- launch ----------------

extern "C" void kernel_launch(void* const* d_in, const int* in_sizes, int n_in,
                              void* d_out, int out_size, void* d_ws, size_t ws_size,
                              hipStream_t stream) {
    const float* x  = (const float*)d_in[0];
    const int*   ei = (const int*)d_in[1];
    const float* W1 = (const float*)d_in[2];
    const float* b1 = (const float*)d_in[3];
    const float* W2 = (const float*)d_in[4];
    const float* b2 = (const float*)d_in[5];
    float* out = (float*)d_out;

    const int n = in_sizes[0] / 128;
    const int E = in_sizes[1] / 2;
    const int* src = ei;
    const int* dst = ei + E;
    const int NB = (n + 255) >> BSHIFT;
    int avg = (E + NB - 1) / NB;
    int CAP = avg + avg / 8 + 512;
    if (CAP > CAP_MAX) CAP = CAP_MAX;

    char* ws = (char*)d_ws;
    size_t woff = 0;
    auto carve = [&](size_t bytes) {
        void* p = ws + woff;
        woff += (bytes + 255) & ~(size_t)255;
        return p;
    };
    int*    bcnt   = (int*)carve((size_t)NB * sizeof(int));
    u32*    binned = (u32*)carve((size_t)NB * CAP * sizeof(u32));
    int2*   offse  = (int2*)carve((size_t)n * sizeof(int2));
    float*  dinv   = (float*)carve((size_t)n * sizeof(float));
    int*    esrc   = (int*)carve((size_t)NB * CAP * sizeof(int));
    bf16x8* Wpack  = (bf16x8*)carve(16 * 64 * sizeof(bf16x8));
    u16*    h1b    = (u16*)carve((size_t)n * 64 * sizeof(u16));
    u16*    h2b    = (u16*)carve((size_t)n * 32 * sizeof(u16));

    const int B = 256;
    const int ntiles16 = (n + 15) / 16;

    hipMemsetAsync(bcnt, 0, (size_t)NB * sizeof(int), stream);
    k_prepW<<<1, 64, 0, stream>>>(W1, Wpack);

    // bucketed CSR build
    k_bin<<<(E + BIN_CHUNK - 1) / BIN_CHUNK, B, 0, stream>>>(src, dst, bcnt, binned, E, NB, CAP);
    k_csr<<<NB, B, 0, stream>>>(binned, bcnt, dinv, offse, esrc, n, CAP);

    // layer 1 transform (MFMA, bf16 out)
    k_gemm1_mfma<<<(ntiles16 + 3) / 4, B, 0, stream>>>(x, Wpack, dinv, h1b, n, ntiles16);

    // fused: aggregate layer 1 + relu + layer-2 transform (bf16 out)
    k_agg1gemm2<<<2048, B, 0, stream>>>(h1b, offse, esrc, dinv, b1, W2, h2b, n);

    // final aggregation + bias -> out (fp32)
    k_agg2<<<(n + 3) / 4, B, 0, stream>>>(h2b, offse, esrc, dinv, b2, out, n);
}

// Round 7
// 164.752 us; speedup vs baseline: 4.6634x; 1.2064x over previous
//
#include <hip/hip_runtime.h>

typedef unsigned int   u32;
typedef unsigned short u16;
typedef __attribute__((ext_vector_type(8))) short bf16x8;
typedef __attribute__((ext_vector_type(4))) float f32x4;

__device__ __forceinline__ u16 f2b(float f) {
    u32 u = __float_as_uint(f);
    u += 0x7FFFu + ((u >> 16) & 1u);   // round-to-nearest-even
    return (u16)(u >> 16);
}
__device__ __forceinline__ float b2f_lo(u32 v) { return __uint_as_float(v << 16); }
__device__ __forceinline__ float b2f_hi(u32 v) { return __uint_as_float(v & 0xFFFF0000u); }
__device__ __forceinline__ u32 pack2(float a, float b) {
    return (u32)f2b(a) | ((u32)f2b(b) << 16);
}

#define BSHIFT 8                      // 256 nodes per bucket
#define BIN_CHUNK 4096                // edges per k_bin block
#define CAP_MAX 8192                  // max padded bucket capacity (LDS stage bound)

// ---------------- bucketed edge binning (padded regions, no scan) ----------------

__global__ __launch_bounds__(256) void k_bin(const int* __restrict__ src,
                                             const int* __restrict__ dst,
                                             int* __restrict__ bcnt,
                                             u32* __restrict__ binned,
                                             int E, int NB, int CAP) {
    __shared__ int lh[512], ls[512], gb[512], sh[256];
    __shared__ u32 stage[BIN_CHUNK];
    __shared__ u16 sbuck[BIN_CHUNK];
    int tid = threadIdx.x;
    int base = blockIdx.x * BIN_CHUNK;
    int cnt = E - base;
    if (cnt > BIN_CHUNK) cnt = BIN_CHUNK;

    for (int i = tid; i < 512; i += 256) lh[i] = 0;
    __syncthreads();

    int bk[16], r[16];
    u32 key[16];
#pragma unroll
    for (int t = 0; t < 16; t++) {
        int i = base + t * 256 + tid;
        bk[t] = -1;
        if (i < E) {
            int dv = dst[i];
            bk[t] = dv >> BSHIFT;
            key[t] = ((u32)(dv & 255) << 24) | (u32)src[i];
            r[t] = atomicAdd(&lh[bk[t]], 1);
        }
    }
    __syncthreads();
    {
        int a0 = lh[2 * tid], a1 = lh[2 * tid + 1];
        int sum2 = a0 + a1;
        sh[tid] = sum2;
        __syncthreads();
        for (int dd = 1; dd < 256; dd <<= 1) {
            int x = tid >= dd ? sh[tid - dd] : 0;
            __syncthreads();
            sh[tid] += x;
            __syncthreads();
        }
        int excl = sh[tid] - sum2;
        ls[2 * tid] = excl;
        ls[2 * tid + 1] = excl + a0;
    }
    for (int b = tid; b < NB; b += 256) {
        int c = lh[b];
        gb[b] = c ? atomicAdd(&bcnt[b], c) : 0;
    }
    __syncthreads();
#pragma unroll
    for (int t = 0; t < 16; t++) {
        if (bk[t] >= 0) {
            int slot = ls[bk[t]] + r[t];
            stage[slot] = key[t];
            sbuck[slot] = (u16)bk[t];
        }
    }
    __syncthreads();
    for (int j = tid; j < cnt; j += 256) {
        u32 e = stage[j];
        int b = sbuck[j];
        int p = gb[b] + (j - ls[b]);
        if (p < CAP) binned[(size_t)b * CAP + p] = e;
    }
}

// one block per bucket: exact per-node CSR slices (offse) + dinv + esrc
__global__ __launch_bounds__(256) void k_csr(const u32* __restrict__ binned,
                                             const int* __restrict__ bcnt,
                                             float* __restrict__ dinv,
                                             int2* __restrict__ offse,
                                             int* __restrict__ esrc,
                                             int n, int CAP) {
    __shared__ int lcnt[256], lcur[256], sh[256];
    __shared__ u32 stagec[CAP_MAX];
    int tid = threadIdx.x;
    int b = blockIdx.x;
    size_t base = (size_t)b * CAP;
    int ecnt = bcnt[b];
    if (ecnt > CAP) ecnt = CAP;
    lcnt[tid] = 0;
    __syncthreads();
    for (int j = tid; j < ecnt; j += 256) {
        u32 e = binned[base + j];
        stagec[j] = e;
        atomicAdd(&lcnt[e >> 24], 1);
    }
    __syncthreads();
    int v = lcnt[tid];
    sh[tid] = v;
    __syncthreads();
    for (int d = 1; d < 256; d <<= 1) {
        int x = tid >= d ? sh[tid - d] : 0;
        __syncthreads();
        sh[tid] += x;
        __syncthreads();
    }
    int excl = sh[tid] - v;
    int node = (b << BSHIFT) + tid;
    if (node < n) {
        offse[node] = make_int2((int)base + excl, (int)base + excl + v);
        dinv[node] = rsqrtf((float)(v + 1));
    }
    lcur[tid] = excl;
    __syncthreads();
    for (int j = tid; j < ecnt; j += 256) {
        u32 e = stagec[j];
        int p = atomicAdd(&lcur[e >> 24], 1);
        esrc[base + p] = (int)(e & 0xFFFFFFu);
    }
}

// ---------------- W1 fragment pre-pack (bf16 MFMA B-fragments) ----------------

__global__ void k_prepW(const float* __restrict__ W1, bf16x8* __restrict__ Wpack) {
    int lane = threadIdx.x;   // 64 threads
#pragma unroll
    for (int ct = 0; ct < 4; ct++) {
#pragma unroll
        for (int ks = 0; ks < 4; ks++) {
            bf16x8 h;
#pragma unroll
            for (int j = 0; j < 8; j++) {
                int k = ks * 32 + ((lane >> 4) << 3) + j;
                int col = ct * 16 + (lane & 15);
                h[j] = (short)f2b(W1[k * 64 + col]);
            }
            Wpack[(ct * 4 + ks) * 64 + lane] = h;
        }
    }
}

// ---------------- gemm1 via MFMA: h1b = bf16((x @ W1) * dinv[row]) ----------------

__global__ __launch_bounds__(256) void k_gemm1_mfma(const float* __restrict__ x,
                                                    const bf16x8* __restrict__ Wpack,
                                                    const float* __restrict__ dinv,
                                                    u16* __restrict__ h1b,
                                                    int n, int ntiles) {
    int gwave = (int)((blockIdx.x * blockDim.x + threadIdx.x) >> 6);
    int lane = threadIdx.x & 63;
    if (gwave >= ntiles) return;
    int rowBase = gwave * 16;

    bf16x8 bfr[16];
#pragma unroll
    for (int f = 0; f < 16; f++) bfr[f] = Wpack[f * 64 + lane];

    f32x4 acc[4];
#pragma unroll
    for (int ct = 0; ct < 4; ct++) acc[ct] = (f32x4){0.f, 0.f, 0.f, 0.f};

    int r0 = rowBase + (lane & 15);
    if (r0 >= n) r0 = n - 1;                 // clamp: D row i only uses A row i
    const float* xr = x + (size_t)r0 * 128 + ((lane >> 4) << 3);

#pragma unroll
    for (int ks = 0; ks < 4; ks++) {
        float4 p0 = *(const float4*)(xr + ks * 32);
        float4 p1 = *(const float4*)(xr + ks * 32 + 4);
        bf16x8 a;
        a[0] = (short)f2b(p0.x); a[1] = (short)f2b(p0.y);
        a[2] = (short)f2b(p0.z); a[3] = (short)f2b(p0.w);
        a[4] = (short)f2b(p1.x); a[5] = (short)f2b(p1.y);
        a[6] = (short)f2b(p1.z); a[7] = (short)f2b(p1.w);
#pragma unroll
        for (int ct = 0; ct < 4; ct++)
            acc[ct] = __builtin_amdgcn_mfma_f32_16x16x32_bf16(a, bfr[ct * 4 + ks], acc[ct], 0, 0, 0);
    }

    int rbase = rowBase + ((lane >> 4) << 2);
#pragma unroll
    for (int r = 0; r < 4; r++) {
        int row = rbase + r;
        float dv = (row < n) ? dinv[row] : 0.f;
#pragma unroll
        for (int ct = 0; ct < 4; ct++) {
            float o = acc[ct][r] * dv;
            float onb = __shfl_xor(o, 1);    // neighbor col
            if (!(lane & 1) && row < n) {
                *(u32*)&h1b[(size_t)row * 64 + ct * 16 + (lane & 15)] = pack2(o, onb);
            }
        }
    }
}

// ---------------- fused agg1 + relu + gemm2 (bf16 gathers, 2-slot R5 structure) ----------------

__global__ __launch_bounds__(256) void k_agg1gemm2(const u16* __restrict__ h1b,
                                                   const int2* __restrict__ offse,
                                                   const int* __restrict__ esrc,
                                                   const float* __restrict__ dinv,
                                                   const float* __restrict__ b1,
                                                   const float* __restrict__ W2,
                                                   u16* __restrict__ h2b, int n) {
    __shared__ float aggL[4][64];
    int warp = threadIdx.x >> 6, lane = threadIdx.x & 63;
    int half = lane >> 5, c2 = lane & 31;
    float w2r[32];
#pragma unroll
    for (int kk = 0; kk < 32; kk++) w2r[kk] = W2[(half * 32 + kk) * 32 + c2];
    float2 bb = *(const float2*)&b1[2 * c2];
    int nwaves = (gridDim.x * blockDim.x) >> 6;
    for (int wid = (int)((blockIdx.x * blockDim.x + threadIdx.x) >> 6); wid < n;
         wid += nwaves) {
        int2 ov = offse[wid];
        int e1 = ov.y;
        float a0 = 0.f, a1 = 0.f, a2 = 0.f, a3 = 0.f;
        if (half == 0) {  // self-loop
            u32 v = *(const u32*)&h1b[(size_t)wid * 64 + 2 * c2];
            a0 += b2f_lo(v); a1 += b2f_hi(v);
        }
        int e = ov.x + half;
        for (; e + 2 < e1; e += 4) {         // 2 slots per half-wave in flight
            int s0 = esrc[e], s1 = esrc[e + 2];
            u32 v0 = *(const u32*)&h1b[(size_t)s0 * 64 + 2 * c2];
            u32 v1 = *(const u32*)&h1b[(size_t)s1 * 64 + 2 * c2];
            a0 += b2f_lo(v0); a1 += b2f_hi(v0);
            a2 += b2f_lo(v1); a3 += b2f_hi(v1);
        }
        if (e < e1) {
            int s = esrc[e];
            u32 v = *(const u32*)&h1b[(size_t)s * 64 + 2 * c2];
            a0 += b2f_lo(v); a1 += b2f_hi(v);
        }
        a0 += a2; a1 += a3;
        a0 += __shfl_xor(a0, 32);
        a1 += __shfl_xor(a1, 32);
        float dv = dinv[wid];
        a0 = a0 * dv + bb.x; a1 = a1 * dv + bb.y;
        a0 = a0 > 0.f ? a0 : 0.f;
        a1 = a1 > 0.f ? a1 : 0.f;
        if (half == 0) *(float2*)&aggL[warp][2 * c2] = make_float2(a0, a1);
        asm volatile("s_waitcnt lgkmcnt(0)" ::: "memory");  // wave-internal sync
        float acc = 0.f;
#pragma unroll
        for (int kk = 0; kk < 32; kk += 4) {
            float4 av = *(const float4*)&aggL[warp][half * 32 + kk];
            acc += av.x * w2r[kk] + av.y * w2r[kk + 1] + av.z * w2r[kk + 2] + av.w * w2r[kk + 3];
        }
        acc += __shfl_xor(acc, 32);
        if (half == 0) h2b[(size_t)wid * 32 + c2] = f2b(acc * dv);
    }
}

// ---------------- final aggregation -> out (bf16 gathers, 2-slot R5 structure) ----------------

__global__ __launch_bounds__(256) void k_agg2(const u16* __restrict__ h2b,
                                              const int2* __restrict__ offse,
                                              const int* __restrict__ esrc,
                                              const float* __restrict__ dinv,
                                              const float* __restrict__ b2,
                                              float* __restrict__ out, int n) {
    int wid = (int)((blockIdx.x * blockDim.x + threadIdx.x) >> 6);
    int lane = threadIdx.x & 63;
    int g = lane >> 4, c2 = lane & 15;
    if (wid >= n) return;
    int2 ov = offse[wid];
    int e1 = ov.y;
    float a0 = 0.f, a1 = 0.f, a2 = 0.f, a3 = 0.f;
    int e = ov.x + g;
    for (; e + 4 < e1; e += 8) {             // 2 slots per quarter-wave in flight
        int s0 = esrc[e], s1 = esrc[e + 4];
        u32 v0 = *(const u32*)&h2b[(size_t)s0 * 32 + 2 * c2];
        u32 v1 = *(const u32*)&h2b[(size_t)s1 * 32 + 2 * c2];
        a0 += b2f_lo(v0); a1 += b2f_hi(v0);
        a2 += b2f_lo(v1); a3 += b2f_hi(v1);
    }
    if (e < e1) {
        int s = esrc[e];
        u32 v = *(const u32*)&h2b[(size_t)s * 32 + 2 * c2];
        a0 += b2f_lo(v); a1 += b2f_hi(v);
    }
    a0 += a2; a1 += a3;
    a0 += __shfl_xor(a0, 16); a0 += __shfl_xor(a0, 32);
    a1 += __shfl_xor(a1, 16); a1 += __shfl_xor(a1, 32);
    if (g == 0) {
        u32 v = *(const u32*)&h2b[(size_t)wid * 32 + 2 * c2];  // self-loop
        a0 += b2f_lo(v); a1 += b2f_hi(v);
        float dv = dinv[wid];
        float2 o = make_float2(a0 * dv + b2[2 * c2], a1 * dv + b2[2 * c2 + 1]);
        *(float2*)&out[(size_t)wid * 32 + 2 * c2] = o;
    }
}

// ---------------- launch ----------------

extern "C" void kernel_launch(void* const* d_in, const int* in_sizes, int n_in,
                              void* d_out, int out_size, void* d_ws, size_t ws_size,
                              hipStream_t stream) {
    const float* x  = (const float*)d_in[0];
    const int*   ei = (const int*)d_in[1];
    const float* W1 = (const float*)d_in[2];
    const float* b1 = (const float*)d_in[3];
    const float* W2 = (const float*)d_in[4];
    const float* b2 = (const float*)d_in[5];
    float* out = (float*)d_out;

    const int n = in_sizes[0] / 128;
    const int E = in_sizes[1] / 2;
    const int* src = ei;
    const int* dst = ei + E;
    const int NB = (n + 255) >> BSHIFT;
    int avg = (E + NB - 1) / NB;
    int CAP = avg + avg / 8 + 512;
    if (CAP > CAP_MAX) CAP = CAP_MAX;

    char* ws = (char*)d_ws;
    size_t woff = 0;
    auto carve = [&](size_t bytes) {
        void* p = ws + woff;
        woff += (bytes + 255) & ~(size_t)255;
        return p;
    };
    int*    bcnt   = (int*)carve((size_t)NB * sizeof(int));
    u32*    binned = (u32*)carve((size_t)NB * CAP * sizeof(u32));
    int2*   offse  = (int2*)carve((size_t)n * sizeof(int2));
    float*  dinv   = (float*)carve((size_t)n * sizeof(float));
    int*    esrc   = (int*)carve((size_t)NB * CAP * sizeof(int));
    bf16x8* Wpack  = (bf16x8*)carve(16 * 64 * sizeof(bf16x8));
    u16*    h1b    = (u16*)carve((size_t)n * 64 * sizeof(u16));
    u16*    h2b    = (u16*)carve((size_t)n * 32 * sizeof(u16));

    const int B = 256;
    const int ntiles16 = (n + 15) / 16;

    hipMemsetAsync(bcnt, 0, (size_t)NB * sizeof(int), stream);
    k_prepW<<<1, 64, 0, stream>>>(W1, Wpack);

    // bucketed CSR build
    k_bin<<<(E + BIN_CHUNK - 1) / BIN_CHUNK, B, 0, stream>>>(src, dst, bcnt, binned, E, NB, CAP);
    k_csr<<<NB, B, 0, stream>>>(binned, bcnt, dinv, offse, esrc, n, CAP);

    // layer 1 transform (MFMA, bf16 out)
    k_gemm1_mfma<<<(ntiles16 + 3) / 4, B, 0, stream>>>(x, Wpack, dinv, h1b, n, ntiles16);

    // fused: aggregate layer 1 + relu + layer-2 transform (bf16 out)
    k_agg1gemm2<<<2048, B, 0, stream>>>(h1b, offse, esrc, dinv, b1, W2, h2b, n);

    // final aggregation + bias -> out (fp32)
    k_agg2<<<(n + 3) / 4, B, 0, stream>>>(h2b, offse, esrc, dinv, b2, out, n);
}

// Round 8
// 164.451 us; speedup vs baseline: 4.6720x; 1.0018x over previous
//
#include <hip/hip_runtime.h>

typedef unsigned int   u32;
typedef unsigned short u16;
typedef __attribute__((ext_vector_type(8))) short bf16x8;
typedef __attribute__((ext_vector_type(4))) float f32x4;

__device__ __forceinline__ u16 f2b(float f) {
    u32 u = __float_as_uint(f);
    u += 0x7FFFu + ((u >> 16) & 1u);   // round-to-nearest-even
    return (u16)(u >> 16);
}
__device__ __forceinline__ float b2f_lo(u32 v) { return __uint_as_float(v << 16); }
__device__ __forceinline__ float b2f_hi(u32 v) { return __uint_as_float(v & 0xFFFF0000u); }
__device__ __forceinline__ u32 pack2(float a, float b) {
    return (u32)f2b(a) | ((u32)f2b(b) << 16);
}

#define BSHIFT 8                      // 256 nodes per bucket
#define BIN_CHUNK 2048                // edges per k_bin block (load balance: ~782 blocks)
#define CAP_MAX 6144                  // max padded bucket capacity (24KB LDS stage)

// ---------------- init: zero bucket counters + pack W1 MFMA B-fragments ----------------
// Wpack[(ct*4+ks)*64 + lane] = 8 bf16: W1[ks*32 + (lane>>4)*8 + j][ct*16 + (lane&15)]

__global__ void k_init(const float* __restrict__ W1, bf16x8* __restrict__ Wpack,
                       int* __restrict__ bcnt, int NB) {
    int tid = threadIdx.x;
    for (int i = tid; i < NB; i += 256) bcnt[i] = 0;
    if (tid < 64) {
        int lane = tid;
#pragma unroll
        for (int ct = 0; ct < 4; ct++) {
#pragma unroll
            for (int ks = 0; ks < 4; ks++) {
                bf16x8 h;
#pragma unroll
                for (int j = 0; j < 8; j++) {
                    int k = ks * 32 + ((lane >> 4) << 3) + j;
                    int col = ct * 16 + (lane & 15);
                    h[j] = (short)f2b(W1[k * 64 + col]);
                }
                Wpack[(ct * 4 + ks) * 64 + lane] = h;
            }
        }
    }
}

// ---------------- bucketed edge binning (padded regions, no scan) ----------------

__global__ __launch_bounds__(256) void k_bin(const int* __restrict__ src,
                                             const int* __restrict__ dst,
                                             int* __restrict__ bcnt,
                                             u32* __restrict__ binned,
                                             int E, int NB, int CAP) {
    __shared__ int lh[512], ls[512], gb[512], sh[256];
    __shared__ u32 stage[BIN_CHUNK];
    __shared__ u16 sbuck[BIN_CHUNK];
    int tid = threadIdx.x;
    int base = blockIdx.x * BIN_CHUNK;
    int cnt = E - base;
    if (cnt > BIN_CHUNK) cnt = BIN_CHUNK;

    for (int i = tid; i < 512; i += 256) lh[i] = 0;
    __syncthreads();

    const int T = BIN_CHUNK / 256;
    int bk[T], r[T];
    u32 key[T];
#pragma unroll
    for (int t = 0; t < T; t++) {
        int i = base + t * 256 + tid;
        bk[t] = -1;
        if (i < E) {
            int dv = dst[i];
            bk[t] = dv >> BSHIFT;
            key[t] = ((u32)(dv & 255) << 24) | (u32)src[i];
            r[t] = atomicAdd(&lh[bk[t]], 1);
        }
    }
    __syncthreads();
    {
        int a0 = lh[2 * tid], a1 = lh[2 * tid + 1];
        int sum2 = a0 + a1;
        sh[tid] = sum2;
        __syncthreads();
        for (int dd = 1; dd < 256; dd <<= 1) {
            int x = tid >= dd ? sh[tid - dd] : 0;
            __syncthreads();
            sh[tid] += x;
            __syncthreads();
        }
        int excl = sh[tid] - sum2;
        ls[2 * tid] = excl;
        ls[2 * tid + 1] = excl + a0;
    }
    for (int b = tid; b < NB; b += 256) {
        int c = lh[b];
        gb[b] = c ? atomicAdd(&bcnt[b], c) : 0;
    }
    __syncthreads();
#pragma unroll
    for (int t = 0; t < T; t++) {
        if (bk[t] >= 0) {
            int slot = ls[bk[t]] + r[t];
            stage[slot] = key[t];
            sbuck[slot] = (u16)bk[t];
        }
    }
    __syncthreads();
    for (int j = tid; j < cnt; j += 256) {
        u32 e = stage[j];
        int b = sbuck[j];
        int p = gb[b] + (j - ls[b]);
        if (p < CAP) binned[(size_t)b * CAP + p] = e;
    }
}

// ---------------- fused CSR + gemm1 ----------------
// one block per bucket. Phase 1: exact per-node CSR slices (offse) + dinv + esrc.
// Phase 2: MFMA transform h1b = bf16((x @ W1) * dinv) for this bucket's 256 rows
// (dinv read from LDS; blocking aligns exactly).

__global__ __launch_bounds__(256) void k_csr_gemm1(const u32* __restrict__ binned,
                                                   const int* __restrict__ bcnt,
                                                   const bf16x8* __restrict__ Wpack,
                                                   const float* __restrict__ x,
                                                   float* __restrict__ dinv,
                                                   int2* __restrict__ offse,
                                                   int* __restrict__ esrc,
                                                   u16* __restrict__ h1b,
                                                   int n, int CAP) {
    __shared__ u32 stagec[CAP_MAX];
    __shared__ int lcnt[256], lcur[256], sh[256];
    __shared__ float dinv_sh[256];
    int tid = threadIdx.x;
    int b = blockIdx.x;
    size_t base = (size_t)b * CAP;
    int nodeBase = b << BSHIFT;
    int ecnt = bcnt[b];
    if (ecnt > CAP) ecnt = CAP;
    lcnt[tid] = 0;
    __syncthreads();
    for (int j = tid; j < ecnt; j += 256) {
        u32 e = binned[base + j];
        stagec[j] = e;
        atomicAdd(&lcnt[e >> 24], 1);
    }
    __syncthreads();
    int v = lcnt[tid];
    sh[tid] = v;
    __syncthreads();
    for (int d = 1; d < 256; d <<= 1) {
        int xx = tid >= d ? sh[tid - d] : 0;
        __syncthreads();
        sh[tid] += xx;
        __syncthreads();
    }
    int excl = sh[tid] - v;
    int node = nodeBase + tid;
    float dvt = rsqrtf((float)(v + 1));
    dinv_sh[tid] = dvt;
    if (node < n) {
        offse[node] = make_int2((int)base + excl, (int)base + excl + v);
        dinv[node] = dvt;
    }
    lcur[tid] = excl;
    __syncthreads();                       // lcur + dinv_sh ready
    for (int j = tid; j < ecnt; j += 256) {
        u32 e = stagec[j];
        int p = atomicAdd(&lcur[e >> 24], 1);
        esrc[base + p] = (int)(e & 0xFFFFFFu);
    }

    // ---- phase 2: gemm1 for this bucket's rows (needs only dinv_sh, synced above) ----
    int wv = tid >> 6, lane = tid & 63;
    bf16x8 bfr[16];
#pragma unroll
    for (int f = 0; f < 16; f++) bfr[f] = Wpack[f * 64 + lane];

    for (int t = wv; t < 16; t += 4) {     // 4 row-tiles of 16 per wave
        int rowBase = nodeBase + t * 16;
        if (rowBase >= n) break;
        f32x4 acc[4];
#pragma unroll
        for (int ct = 0; ct < 4; ct++) acc[ct] = (f32x4){0.f, 0.f, 0.f, 0.f};

        int r0 = rowBase + (lane & 15);
        if (r0 >= n) r0 = n - 1;           // clamp: D row i only uses A row i
        const float* xr = x + (size_t)r0 * 128 + ((lane >> 4) << 3);
#pragma unroll
        for (int ks = 0; ks < 4; ks++) {
            float4 p0 = *(const float4*)(xr + ks * 32);
            float4 p1 = *(const float4*)(xr + ks * 32 + 4);
            bf16x8 a;
            a[0] = (short)f2b(p0.x); a[1] = (short)f2b(p0.y);
            a[2] = (short)f2b(p0.z); a[3] = (short)f2b(p0.w);
            a[4] = (short)f2b(p1.x); a[5] = (short)f2b(p1.y);
            a[6] = (short)f2b(p1.z); a[7] = (short)f2b(p1.w);
#pragma unroll
            for (int ct = 0; ct < 4; ct++)
                acc[ct] = __builtin_amdgcn_mfma_f32_16x16x32_bf16(a, bfr[ct * 4 + ks], acc[ct], 0, 0, 0);
        }
        // C/D layout: col = lane&15, row = (lane>>4)*4 + r  [m89-verified]
        int lrb = t * 16 + ((lane >> 4) << 2);
#pragma unroll
        for (int r = 0; r < 4; r++) {
            int lrow = lrb + r;
            int row = nodeBase + lrow;
            float dv = dinv_sh[lrow];
#pragma unroll
            for (int ct = 0; ct < 4; ct++) {
                float o = acc[ct][r] * dv;
                float onb = __shfl_xor(o, 1);   // neighbor col
                if (!(lane & 1) && row < n) {
                    *(u32*)&h1b[(size_t)row * 64 + ct * 16 + (lane & 15)] = pack2(o, onb);
                }
            }
        }
    }
}

// ---------------- fused agg1 + relu + gemm2 (bf16 gathers, 2-slot) ----------------

__global__ __launch_bounds__(256) void k_agg1gemm2(const u16* __restrict__ h1b,
                                                   const int2* __restrict__ offse,
                                                   const int* __restrict__ esrc,
                                                   const float* __restrict__ dinv,
                                                   const float* __restrict__ b1,
                                                   const float* __restrict__ W2,
                                                   u16* __restrict__ h2b, int n) {
    __shared__ float aggL[4][64];
    int warp = threadIdx.x >> 6, lane = threadIdx.x & 63;
    int half = lane >> 5, c2 = lane & 31;
    float w2r[32];
#pragma unroll
    for (int kk = 0; kk < 32; kk++) w2r[kk] = W2[(half * 32 + kk) * 32 + c2];
    float2 bb = *(const float2*)&b1[2 * c2];
    int nwaves = (gridDim.x * blockDim.x) >> 6;
    for (int wid = (int)((blockIdx.x * blockDim.x + threadIdx.x) >> 6); wid < n;
         wid += nwaves) {
        int2 ov = offse[wid];
        int e1 = ov.y;
        float a0 = 0.f, a1 = 0.f, a2 = 0.f, a3 = 0.f;
        if (half == 0) {  // self-loop
            u32 v = *(const u32*)&h1b[(size_t)wid * 64 + 2 * c2];
            a0 += b2f_lo(v); a1 += b2f_hi(v);
        }
        int e = ov.x + half;
        for (; e + 2 < e1; e += 4) {         // 2 slots per half-wave in flight
            int s0 = esrc[e], s1 = esrc[e + 2];
            u32 v0 = *(const u32*)&h1b[(size_t)s0 * 64 + 2 * c2];
            u32 v1 = *(const u32*)&h1b[(size_t)s1 * 64 + 2 * c2];
            a0 += b2f_lo(v0); a1 += b2f_hi(v0);
            a2 += b2f_lo(v1); a3 += b2f_hi(v1);
        }
        if (e < e1) {
            int s = esrc[e];
            u32 v = *(const u32*)&h1b[(size_t)s * 64 + 2 * c2];
            a0 += b2f_lo(v); a1 += b2f_hi(v);
        }
        a0 += a2; a1 += a3;
        a0 += __shfl_xor(a0, 32);
        a1 += __shfl_xor(a1, 32);
        float dv = dinv[wid];
        a0 = a0 * dv + bb.x; a1 = a1 * dv + bb.y;
        a0 = a0 > 0.f ? a0 : 0.f;
        a1 = a1 > 0.f ? a1 : 0.f;
        if (half == 0) *(float2*)&aggL[warp][2 * c2] = make_float2(a0, a1);
        asm volatile("s_waitcnt lgkmcnt(0)" ::: "memory");  // wave-internal sync
        float acc = 0.f;
#pragma unroll
        for (int kk = 0; kk < 32; kk += 4) {
            float4 av = *(const float4*)&aggL[warp][half * 32 + kk];
            acc += av.x * w2r[kk] + av.y * w2r[kk + 1] + av.z * w2r[kk + 2] + av.w * w2r[kk + 3];
        }
        acc += __shfl_xor(acc, 32);
        if (half == 0) h2b[(size_t)wid * 32 + c2] = f2b(acc * dv);
    }
}

// ---------------- final aggregation -> out (bf16 gathers, 2-slot) ----------------

__global__ __launch_bounds__(256) void k_agg2(const u16* __restrict__ h2b,
                                              const int2* __restrict__ offse,
                                              const int* __restrict__ esrc,
                                              const float* __restrict__ dinv,
                                              const float* __restrict__ b2,
                                              float* __restrict__ out, int n) {
    int wid = (int)((blockIdx.x * blockDim.x + threadIdx.x) >> 6);
    int lane = threadIdx.x & 63;
    int g = lane >> 4, c2 = lane & 15;
    if (wid >= n) return;
    int2 ov = offse[wid];
    int e1 = ov.y;
    float a0 = 0.f, a1 = 0.f, a2 = 0.f, a3 = 0.f;
    int e = ov.x + g;
    for (; e + 4 < e1; e += 8) {             // 2 slots per quarter-wave in flight
        int s0 = esrc[e], s1 = esrc[e + 4];
        u32 v0 = *(const u32*)&h2b[(size_t)s0 * 32 + 2 * c2];
        u32 v1 = *(const u32*)&h2b[(size_t)s1 * 32 + 2 * c2];
        a0 += b2f_lo(v0); a1 += b2f_hi(v0);
        a2 += b2f_lo(v1); a3 += b2f_hi(v1);
    }
    if (e < e1) {
        int s = esrc[e];
        u32 v = *(const u32*)&h2b[(size_t)s * 32 + 2 * c2];
        a0 += b2f_lo(v); a1 += b2f_hi(v);
    }
    a0 += a2; a1 += a3;
    a0 += __shfl_xor(a0, 16); a0 += __shfl_xor(a0, 32);
    a1 += __shfl_xor(a1, 16); a1 += __shfl_xor(a1, 32);
    if (g == 0) {
        u32 v = *(const u32*)&h2b[(size_t)wid * 32 + 2 * c2];  // self-loop
        a0 += b2f_lo(v); a1 += b2f_hi(v);
        float dv = dinv[wid];
        float2 o = make_float2(a0 * dv + b2[2 * c2], a1 * dv + b2[2 * c2 + 1]);
        *(float2*)&out[(size_t)wid * 32 + 2 * c2] = o;
    }
}

// ---------------- launch ----------------

extern "C" void kernel_launch(void* const* d_in, const int* in_sizes, int n_in,
                              void* d_out, int out_size, void* d_ws, size_t ws_size,
                              hipStream_t stream) {
    const float* x  = (const float*)d_in[0];
    const int*   ei = (const int*)d_in[1];
    const float* W1 = (const float*)d_in[2];
    const float* b1 = (const float*)d_in[3];
    const float* W2 = (const float*)d_in[4];
    const float* b2 = (const float*)d_in[5];
    float* out = (float*)d_out;

    const int n = in_sizes[0] / 128;
    const int E = in_sizes[1] / 2;
    const int* src = ei;
    const int* dst = ei + E;
    const int NB = (n + 255) >> BSHIFT;
    int avg = (E + NB - 1) / NB;
    int CAP = avg + avg / 8 + 512;
    if (CAP > CAP_MAX) CAP = CAP_MAX;

    char* ws = (char*)d_ws;
    size_t woff = 0;
    auto carve = [&](size_t bytes) {
        void* p = ws + woff;
        woff += (bytes + 255) & ~(size_t)255;
        return p;
    };
    int*    bcnt   = (int*)carve((size_t)NB * sizeof(int));
    u32*    binned = (u32*)carve((size_t)NB * CAP * sizeof(u32));
    int2*   offse  = (int2*)carve((size_t)n * sizeof(int2));
    float*  dinv   = (float*)carve((size_t)n * sizeof(float));
    int*    esrc   = (int*)carve((size_t)NB * CAP * sizeof(int));
    bf16x8* Wpack  = (bf16x8*)carve(16 * 64 * sizeof(bf16x8));
    u16*    h1b    = (u16*)carve((size_t)n * 64 * sizeof(u16));
    u16*    h2b    = (u16*)carve((size_t)n * 32 * sizeof(u16));

    const int B = 256;

    // init (zero bcnt + pack W1 fragments)
    k_init<<<1, B, 0, stream>>>(W1, Wpack, bcnt, NB);

    // bucketed binning
    k_bin<<<(E + BIN_CHUNK - 1) / BIN_CHUNK, B, 0, stream>>>(src, dst, bcnt, binned, E, NB, CAP);

    // fused CSR build + layer-1 MFMA transform (bf16 out)
    k_csr_gemm1<<<NB, B, 0, stream>>>(binned, bcnt, Wpack, x, dinv, offse, esrc, h1b, n, CAP);

    // fused: aggregate layer 1 + relu + layer-2 transform (bf16 out)
    k_agg1gemm2<<<2048, B, 0, stream>>>(h1b, offse, esrc, dinv, b1, W2, h2b, n);

    // final aggregation + bias -> out (fp32)
    k_agg2<<<(n + 3) / 4, B, 0, stream>>>(h2b, offse, esrc, dinv, b2, out, n);
}